// Round 1
// baseline (474.056 us; speedup 1.0000x reference)
//
#include <hip/hip_runtime.h>
#include <hip/hip_bf16.h>

typedef __attribute__((ext_vector_type(8))) __bf16 bf16x8;
typedef __attribute__((ext_vector_type(4))) __bf16 bf16x4;
typedef __attribute__((ext_vector_type(4))) float  f32x4;

// ---------------------------------------------------------------------------
// async global->LDS, 16B per lane. LDS dest must be wave-uniform base.
__device__ __forceinline__ void gl_lds16(const __bf16* g, __bf16* l) {
  __builtin_amdgcn_global_load_lds(
      (const __attribute__((address_space(1))) void*)g,
      (__attribute__((address_space(3))) void*)l,
      16, 0, 0);
}

// ---------------------------------------------------------------------------
// f32 -> bf16 conversion, float4 vectorized
__global__ void f2bf_kernel(const float* __restrict__ in, __bf16* __restrict__ out, int n4) {
  int i = blockIdx.x * blockDim.x + threadIdx.x;
  if (i >= n4) return;
  float4 v = ((const float4*)in)[i];
  bf16x4 o;
  o[0] = (__bf16)v.x; o[1] = (__bf16)v.y; o[2] = (__bf16)v.z; o[3] = (__bf16)v.w;
  *(bf16x4*)(out + 4L * i) = o;
}

// gen (512 x 2047) f32 -> genT (2048 x 512) bf16, row 2047 zero-padded
__global__ void genT_kernel(const float* __restrict__ gen, __bf16* __restrict__ genT) {
  int i = blockIdx.x; // 0..2047
  for (int d = threadIdx.x; d < 512; d += blockDim.x) {
    float v = (i < 2047) ? gen[(long)d * 2047 + i] : 0.f;
    genT[(long)i * 512 + d] = (__bf16)v;
  }
}

// G2T[i][k] = sum_d Wq[d][k] * gen[d][992+i],  i in [0,63)  (f32 exact path)
__global__ void g2t_kernel(const float* __restrict__ Wq, const float* __restrict__ gen,
                           float* __restrict__ g2t) {
  int i = blockIdx.x;   // 0..62
  int k = threadIdx.x;  // 0..255
  float a0 = 0.f, a1 = 0.f;
  for (int d = 0; d < 512; ++d) {
    float g = gen[(long)d * 2047 + 992 + i];
    a0 += Wq[(long)d * 512 + k] * g;
    a1 += Wq[(long)d * 512 + k + 256] * g;
  }
  g2t[(long)i * 512 + k] = a0;
  g2t[(long)i * 512 + k + 256] = a1;
}

// ---------------------------------------------------------------------------
// bf16 GEMM, C = A @ B^T.  A: (M x K) row-major, B stored (N x K) row-major.
// 128x128 tile, BK=32, 4 waves, mfma_f32_16x16x32_bf16 (m97 structure).
// MODE 0: store f32 C (ldc=N).      MODE 1: store bf16 C (ldc=N).
// MODE 2: store bf16 C^T per batch-of-1024-rows: C[(m>>10)*512+n][m&1023] (vT).
// MODE 3: bf16 C scaled per-row by 1/(aux[row]+1e-8).
template <int MODE>
__global__ __launch_bounds__(256) void gemm_bt(
    const __bf16* __restrict__ A, const __bf16* __restrict__ B, void* __restrict__ Cv,
    const float* __restrict__ aux, int N, int K, long sA, long sB, long sC, int sAux) {
  __shared__ __bf16 As[128 * 32];
  __shared__ __bf16 Bs[128 * 32];
  const int tid = threadIdx.x;
  const int w = tid >> 6, l = tid & 63;
  const int m0 = blockIdx.y * 128, n0 = blockIdx.x * 128;
  const int bz = blockIdx.z;
  const __bf16* Ab = A + (long)bz * sA;
  const __bf16* Bb = B + (long)bz * sB;

  const int srow = w * 16 + (l >> 2);   // staging row within 64-row half
  const int scol = (l & 3) * 8;         // staging col (8 bf16 = 16B)
  const int wr = (w >> 1) * 64, wc = (w & 1) * 64;
  const int fr = l & 15, fk = (l >> 4) * 8;

  f32x4 acc[4][4] = {};

  for (int k0 = 0; k0 < K; k0 += 32) {
    __syncthreads();
    gl_lds16(Ab + (long)(m0 + srow) * K + (k0 + scol),      &As[(w * 16) * 32]);
    gl_lds16(Ab + (long)(m0 + 64 + srow) * K + (k0 + scol), &As[(64 + w * 16) * 32]);
    gl_lds16(Bb + (long)(n0 + srow) * K + (k0 + scol),      &Bs[(w * 16) * 32]);
    gl_lds16(Bb + (long)(n0 + 64 + srow) * K + (k0 + scol), &Bs[(64 + w * 16) * 32]);
    __syncthreads();

    bf16x8 af[4], bg[4];
#pragma unroll
    for (int i = 0; i < 4; ++i) af[i] = *(const bf16x8*)&As[(wr + i * 16 + fr) * 32 + fk];
#pragma unroll
    for (int j = 0; j < 4; ++j) bg[j] = *(const bf16x8*)&Bs[(wc + j * 16 + fr) * 32 + fk];
#pragma unroll
    for (int i = 0; i < 4; ++i)
#pragma unroll
      for (int j = 0; j < 4; ++j)
        acc[i][j] = __builtin_amdgcn_mfma_f32_16x16x32_bf16(af[i], bg[j], acc[i][j], 0, 0, 0);
  }

  const int rbase = m0 + wr + ((l >> 4) << 2);
  const int cbase = n0 + wc + fr;

  if constexpr (MODE == 0) {
    float* C = (float*)Cv + (long)bz * sC;
#pragma unroll
    for (int i = 0; i < 4; ++i)
#pragma unroll
      for (int r = 0; r < 4; ++r) {
        long row = rbase + i * 16 + r;
#pragma unroll
        for (int j = 0; j < 4; ++j) C[row * N + cbase + j * 16] = acc[i][j][r];
      }
  } else if constexpr (MODE == 1) {
    __bf16* C = (__bf16*)Cv + (long)bz * sC;
#pragma unroll
    for (int i = 0; i < 4; ++i)
#pragma unroll
      for (int r = 0; r < 4; ++r) {
        long row = rbase + i * 16 + r;
#pragma unroll
        for (int j = 0; j < 4; ++j) C[row * N + cbase + j * 16] = (__bf16)acc[i][j][r];
      }
  } else if constexpr (MODE == 2) {
    __bf16* C = (__bf16*)Cv;
#pragma unroll
    for (int i = 0; i < 4; ++i) {
      int gm = rbase + i * 16;
      int bt = gm >> 10, lloc = gm & 1023;
#pragma unroll
      for (int j = 0; j < 4; ++j) {
        bf16x4 pk;
        pk[0] = (__bf16)acc[i][j][0]; pk[1] = (__bf16)acc[i][j][1];
        pk[2] = (__bf16)acc[i][j][2]; pk[3] = (__bf16)acc[i][j][3];
        *(bf16x4*)&C[((long)bt * 512 + cbase + j * 16) * 1024 + lloc] = pk;
      }
    }
  } else { // MODE 3
    __bf16* C = (__bf16*)Cv + (long)bz * sC;
    const float* ax = aux + (long)bz * sAux;
#pragma unroll
    for (int i = 0; i < 4; ++i)
#pragma unroll
      for (int r = 0; r < 4; ++r) {
        long row = rbase + i * 16 + r;
        float sc = 1.f / (ax[row] + 1e-8f);
#pragma unroll
        for (int j = 0; j < 4; ++j) C[row * N + cbase + j * 16] = (__bf16)(acc[i][j][r] * sc);
      }
  }
}

// ---------------------------------------------------------------------------
// S[b,l,j] = w_full[b,l,1023-l+j].  Two-level cumsum over l.
// Phase 1: per-chunk (256 l's) column sums.
__global__ void chunk_sums(const __bf16* __restrict__ wfull, float* __restrict__ csum) {
  int j = blockIdx.x * 256 + threadIdx.x;
  int c = blockIdx.y, b = blockIdx.z;
  const __bf16* base = wfull + (long)b * 1024 * 2048;
  float acc = 0.f;
  int l0 = c * 256;
  for (int l = l0; l < l0 + 256; ++l)
    acc += (float)base[(long)l * 2048 + 1023 - l + j];
  csum[((long)(b * 4 + c) << 10) + j] = acc;
}

// Phase 2: in-place exclusive scan over the 4 chunks per (b,j)
__global__ void scan_kernel(float* __restrict__ csum) {
  int idx = blockIdx.x * 256 + threadIdx.x; // 0..16383
  int b = idx >> 10, j = idx & 1023;
  float s = 0.f;
  for (int c = 0; c < 4; ++c) {
    long o = ((long)(b * 4 + c) << 10) + j;
    float t = csum[o];
    csum[o] = s;
    s += t;
  }
}

// Phase 3: walk chunk with offset, relu+tril, store bf16 weights, rowsum atomics
__global__ void cumsum_relu(const __bf16* __restrict__ wfull, const float* __restrict__ csum,
                            __bf16* __restrict__ wrelu, float* __restrict__ rowsum) {
  int j = blockIdx.x * 256 + threadIdx.x;
  int c = blockIdx.y, b = blockIdx.z;
  float run = csum[((long)(b * 4 + c) << 10) + j];
  const __bf16* base = wfull + (long)b * 1024 * 2048;
  __bf16* wr = wrelu + (long)b * 1024 * 1024;
  int l0 = c * 256;
  for (int l = l0; l < l0 + 256; ++l) {
    run += (float)base[(long)l * 2048 + 1023 - l + j];
    float v = (j <= l) ? fmaxf(run, 0.f) : 0.f;
    wr[(long)l * 1024 + j] = (__bf16)v;
    float s = v;
#pragma unroll
    for (int off = 32; off; off >>= 1) s += __shfl_down(s, off);
    if ((threadIdx.x & 63) == 0 && s != 0.f) atomicAdd(&rowsum[b * 1024 + l], s);
  }
}

// ---------------------------------------------------------------------------
// Exact f32 recompute of rows l<32 (sign-flip hazard region). One block per b.
__global__ void small_fix(const float* __restrict__ x, const float* __restrict__ g2t,
                          __bf16* __restrict__ wrelu, float* __restrict__ rowsum) {
  int b = blockIdx.x;
  int tid = threadIdx.x;
  __shared__ float S[32][33];
  for (int e = tid; e < 1024; e += 256) {
    int m = e >> 5, j = e & 31;
    const float4* xr = (const float4*)(x + ((long)b * 1024 + m) * 512);
    const float4* gr = (const float4*)(g2t + (long)(31 - m + j) * 512);
    float s = 0.f;
    for (int t = 0; t < 128; ++t) {
      float4 a = xr[t], c = gr[t];
      s += a.x * c.x + a.y * c.y + a.z * c.z + a.w * c.w;
    }
    S[m][j] = s;
  }
  __syncthreads();
  if (tid < 32) { // cumsum over m for column j=tid
    int j = tid;
    float run = 0.f;
    for (int m = 0; m < 32; ++m) { run += S[m][j]; S[m][j] = run; }
  }
  __syncthreads();
  if (tid < 32) { // row l=tid: relu/tril, exact rowsum, overwrite
    int l = tid;
    float rs = 0.f;
    for (int j = 0; j <= l; ++j) rs += fmaxf(S[l][j], 0.f);
    rowsum[b * 1024 + l] = rs;
    __bf16* wr = wrelu + ((long)b * 1024 + l) * 1024;
    for (int j = 0; j < 32; ++j) {
      float v = (j <= l) ? fmaxf(S[l][j], 0.f) : 0.f;
      wr[j] = (__bf16)v;
    }
  }
}

// ---------------------------------------------------------------------------
extern "C" void kernel_launch(void* const* d_in, const int* in_sizes, int n_in,
                              void* d_out, int out_size, void* d_ws, size_t ws_size,
                              hipStream_t stream) {
  const float* x   = (const float*)d_in[0];
  const float* gen = (const float*)d_in[1];
  const float* Wq  = (const float*)d_in[2];
  const float* Wv  = (const float*)d_in[3];
  const float* Wc  = (const float*)d_in[4];

  char* ws = (char*)d_ws;
  __bf16* xb    = (__bf16*)(ws + 0L);
  __bf16* qb    = (__bf16*)(ws + 16777216L);
  __bf16* vT    = (__bf16*)(ws + 33554432L);
  __bf16* outn  = (__bf16*)(ws + 50331648L);
  __bf16* wfull = (__bf16*)(ws + 67108864L);
  __bf16* wrelu = (__bf16*)(ws + 134217728L);
  __bf16* genT  = (__bf16*)(ws + 167772160L);
  __bf16* wqb   = (__bf16*)(ws + 169869312L);
  __bf16* wvb   = (__bf16*)(ws + 170393600L);
  __bf16* wcb   = (__bf16*)(ws + 170917888L);
  float*  csum  = (float*)(ws + 171442176L);
  float*  rsum  = (float*)(ws + 171704320L);
  float*  g2t   = (float*)(ws + 171769856L);

  // conversions
  f2bf_kernel<<<8192, 256, 0, stream>>>(x, xb, 2097152);
  f2bf_kernel<<<256, 256, 0, stream>>>(Wq, wqb, 65536);
  f2bf_kernel<<<256, 256, 0, stream>>>(Wv, wvb, 65536);
  f2bf_kernel<<<256, 256, 0, stream>>>(Wc, wcb, 65536);
  genT_kernel<<<2048, 256, 0, stream>>>(gen, genT);
  g2t_kernel<<<63, 256, 0, stream>>>(Wq, gen, g2t);

  // q = x@Wq^T ; vT = (x@Wv^T)^T per batch ; w_full = q@genT^T
  gemm_bt<1><<<dim3(4, 128, 1), 256, 0, stream>>>(xb, wqb, qb, nullptr, 512, 512, 0, 0, 0, 0);
  gemm_bt<2><<<dim3(4, 128, 1), 256, 0, stream>>>(xb, wvb, vT, nullptr, 512, 512, 0, 0, 0, 0);
  gemm_bt<1><<<dim3(16, 128, 1), 256, 0, stream>>>(qb, genT, wfull, nullptr, 2048, 512, 0, 0, 0, 0);

  // gather + cumsum + relu/tril + rowsum
  chunk_sums<<<dim3(4, 4, 16), 256, 0, stream>>>(wfull, csum);
  scan_kernel<<<64, 256, 0, stream>>>(csum);
  hipMemsetAsync(rsum, 0, 16 * 1024 * 4, stream);
  cumsum_relu<<<dim3(4, 4, 16), 256, 0, stream>>>(wfull, csum, wrelu, rsum);
  small_fix<<<16, 256, 0, stream>>>(x, g2t, wrelu, rsum);

  // OUT = normalize(Wrelu) @ v  (batched), then Y = OUT @ Wc^T -> f32 d_out
  gemm_bt<3><<<dim3(4, 8, 16), 256, 0, stream>>>(wrelu, vT, outn, rsum, 512, 1024,
                                                 1024L * 1024, 512L * 1024, 512L * 1024, 1024);
  gemm_bt<0><<<dim3(4, 128, 1), 256, 0, stream>>>(outn, wcb, d_out, nullptr, 512, 512, 0, 0, 0, 0);
}

// Round 2
// 294.384 us; speedup vs baseline: 1.6103x; 1.6103x over previous
//
#include <hip/hip_runtime.h>
#include <hip/hip_bf16.h>

typedef __attribute__((ext_vector_type(8))) __bf16 bf16x8;
typedef __attribute__((ext_vector_type(4))) __bf16 bf16x4;
typedef __attribute__((ext_vector_type(4))) float  f32x4;

// ---------------------------------------------------------------------------
// async global->LDS, 16B per lane. LDS dest must be wave-uniform base.
__device__ __forceinline__ void gl_lds16(const __bf16* g, __bf16* l) {
  __builtin_amdgcn_global_load_lds(
      (const __attribute__((address_space(1))) void*)g,
      (__attribute__((address_space(3))) void*)l,
      16, 0, 0);
}

// ---------------------------------------------------------------------------
// f32 -> bf16 conversion, float4 vectorized
__global__ void f2bf_kernel(const float* __restrict__ in, __bf16* __restrict__ out, int n4) {
  int i = blockIdx.x * blockDim.x + threadIdx.x;
  if (i >= n4) return;
  float4 v = ((const float4*)in)[i];
  bf16x4 o;
  o[0] = (__bf16)v.x; o[1] = (__bf16)v.y; o[2] = (__bf16)v.z; o[3] = (__bf16)v.w;
  *(bf16x4*)(out + 4L * i) = o;
}

// gen (512 x 2047) f32 -> genT (2048 x 512) bf16, row 2047 zero-padded
__global__ void genT_kernel(const float* __restrict__ gen, __bf16* __restrict__ genT) {
  int i = blockIdx.x; // 0..2047
  for (int d = threadIdx.x; d < 512; d += blockDim.x) {
    float v = (i < 2047) ? gen[(long)d * 2047 + i] : 0.f;
    genT[(long)i * 512 + d] = (__bf16)v;
  }
}

// G2T[i][k] = sum_d Wq[d][k] * gen[d][992+i],  i in [0,63)  (f32 exact path)
__global__ void g2t_kernel(const float* __restrict__ Wq, const float* __restrict__ gen,
                           float* __restrict__ g2t) {
  int i = blockIdx.x;   // 0..62
  int k = threadIdx.x;  // 0..255
  float a0 = 0.f, a1 = 0.f;
  for (int d = 0; d < 512; ++d) {
    float g = gen[(long)d * 2047 + 992 + i];
    a0 += Wq[(long)d * 512 + k] * g;
    a1 += Wq[(long)d * 512 + k + 256] * g;
  }
  g2t[(long)i * 512 + k] = a0;
  g2t[(long)i * 512 + k + 256] = a1;
}

// ---------------------------------------------------------------------------
// bf16 GEMM, C = A @ B^T.  A: (M x K) row-major, B stored (N x K) row-major.
// 128x128 tile, BK=32, 4 waves, mfma_f32_16x16x32_bf16 (m97 structure).
// MODE 0: store f32 C (ldc=N).      MODE 1: store bf16 C (ldc=N).
// MODE 2: store bf16 C^T per batch-of-1024-rows: C[(m>>10)*512+n][m&1023] (vT).
// MODE 3: bf16 C scaled per-row by 1/(aux[row]+1e-8).
// DIAG: trapezoid n-tile mapping for the w_full band (9 n-tiles per m-tile).
template <int MODE, bool DIAG = false>
__global__ __launch_bounds__(256) void gemm_bt(
    const __bf16* __restrict__ A, const __bf16* __restrict__ B, void* __restrict__ Cv,
    const float* __restrict__ aux, int N, int K, long sA, long sB, long sC, int sAux) {
  __shared__ __bf16 As[128 * 32];
  __shared__ __bf16 Bs[128 * 32];
  const int tid = threadIdx.x;
  const int w = tid >> 6, l = tid & 63;
  const int m0 = blockIdx.y * 128;
  const int n0 = DIAG ? (7 - (int)(blockIdx.y & 7) + (int)blockIdx.x) * 128
                      : blockIdx.x * 128;
  const int bz = blockIdx.z;
  const __bf16* Ab = A + (long)bz * sA;
  const __bf16* Bb = B + (long)bz * sB;

  const int srow = w * 16 + (l >> 2);   // staging row within 64-row half
  const int scol = (l & 3) * 8;         // staging col (8 bf16 = 16B)
  const int wr = (w >> 1) * 64, wc = (w & 1) * 64;
  const int fr = l & 15, fk = (l >> 4) * 8;

  f32x4 acc[4][4] = {};

  for (int k0 = 0; k0 < K; k0 += 32) {
    __syncthreads();
    gl_lds16(Ab + (long)(m0 + srow) * K + (k0 + scol),      &As[(w * 16) * 32]);
    gl_lds16(Ab + (long)(m0 + 64 + srow) * K + (k0 + scol), &As[(64 + w * 16) * 32]);
    gl_lds16(Bb + (long)(n0 + srow) * K + (k0 + scol),      &Bs[(w * 16) * 32]);
    gl_lds16(Bb + (long)(n0 + 64 + srow) * K + (k0 + scol), &Bs[(64 + w * 16) * 32]);
    __syncthreads();

    bf16x8 af[4], bg[4];
#pragma unroll
    for (int i = 0; i < 4; ++i) af[i] = *(const bf16x8*)&As[(wr + i * 16 + fr) * 32 + fk];
#pragma unroll
    for (int j = 0; j < 4; ++j) bg[j] = *(const bf16x8*)&Bs[(wc + j * 16 + fr) * 32 + fk];
#pragma unroll
    for (int i = 0; i < 4; ++i)
#pragma unroll
      for (int j = 0; j < 4; ++j)
        acc[i][j] = __builtin_amdgcn_mfma_f32_16x16x32_bf16(af[i], bg[j], acc[i][j], 0, 0, 0);
  }

  const int rbase = m0 + wr + ((l >> 4) << 2);
  const int cbase = n0 + wc + fr;

  if constexpr (MODE == 0) {
    float* C = (float*)Cv + (long)bz * sC;
#pragma unroll
    for (int i = 0; i < 4; ++i)
#pragma unroll
      for (int r = 0; r < 4; ++r) {
        long row = rbase + i * 16 + r;
#pragma unroll
        for (int j = 0; j < 4; ++j) C[row * N + cbase + j * 16] = acc[i][j][r];
      }
  } else if constexpr (MODE == 1) {
    __bf16* C = (__bf16*)Cv + (long)bz * sC;
#pragma unroll
    for (int i = 0; i < 4; ++i)
#pragma unroll
      for (int r = 0; r < 4; ++r) {
        long row = rbase + i * 16 + r;
#pragma unroll
        for (int j = 0; j < 4; ++j) C[row * N + cbase + j * 16] = (__bf16)acc[i][j][r];
      }
  } else if constexpr (MODE == 2) {
    __bf16* C = (__bf16*)Cv;
#pragma unroll
    for (int i = 0; i < 4; ++i) {
      int gm = rbase + i * 16;
      int bt = gm >> 10, lloc = gm & 1023;
#pragma unroll
      for (int j = 0; j < 4; ++j) {
        bf16x4 pk;
        pk[0] = (__bf16)acc[i][j][0]; pk[1] = (__bf16)acc[i][j][1];
        pk[2] = (__bf16)acc[i][j][2]; pk[3] = (__bf16)acc[i][j][3];
        *(bf16x4*)&C[((long)bt * 512 + cbase + j * 16) * 1024 + lloc] = pk;
      }
    }
  } else { // MODE 3
    __bf16* C = (__bf16*)Cv + (long)bz * sC;
    const float* ax = aux + (long)bz * sAux;
#pragma unroll
    for (int i = 0; i < 4; ++i)
#pragma unroll
      for (int r = 0; r < 4; ++r) {
        long row = rbase + i * 16 + r;
        float sc = 1.f / (ax[row] + 1e-8f);
#pragma unroll
        for (int j = 0; j < 4; ++j) C[row * N + cbase + j * 16] = (__bf16)(acc[i][j][r] * sc);
      }
  }
}

// ---------------------------------------------------------------------------
// S[b,l,j] = w_full[b,l,1023-l+j].  Two-level cumsum over l, 16 chunks of 64.
// Phase 1: per-chunk column sums.
__global__ void chunk_sums(const __bf16* __restrict__ wfull, float* __restrict__ csum) {
  int j = blockIdx.x * 256 + threadIdx.x;
  int c = blockIdx.y, b = blockIdx.z;
  const __bf16* base = wfull + (long)b * 1024 * 2048;
  float acc = 0.f;
  int l0 = c * 64;
  for (int l = l0; l < l0 + 64; ++l)
    acc += (float)base[(long)l * 2048 + 1023 - l + j];
  csum[((long)(b * 16 + c) << 10) + j] = acc;
}

// Phase 2: register exclusive scan over the 16 chunks per (b,j)
__global__ void scan_kernel(float* __restrict__ csum) {
  int idx = blockIdx.x * 256 + threadIdx.x; // 0..16383
  int b = idx >> 10, j = idx & 1023;
  long base = ((long)b * 16 << 10) + j;
  float v[16];
#pragma unroll
  for (int c = 0; c < 16; ++c) v[c] = csum[base + ((long)c << 10)];
  float s = 0.f;
#pragma unroll
  for (int c = 0; c < 16; ++c) { float t = v[c]; csum[base + ((long)c << 10)] = s; s += t; }
}

// Phase 3: walk chunk with offset, relu+tril, store bf16 weights
__global__ void cumsum_relu(const __bf16* __restrict__ wfull, const float* __restrict__ csum,
                            __bf16* __restrict__ wrelu) {
  int j = blockIdx.x * 256 + threadIdx.x;
  int c = blockIdx.y, b = blockIdx.z;
  float run = csum[((long)(b * 16 + c) << 10) + j];
  const __bf16* base = wfull + (long)b * 1024 * 2048;
  __bf16* wr = wrelu + (long)b * 1024 * 1024;
  int l0 = c * 64;
  for (int l = l0; l < l0 + 64; ++l) {
    run += (float)base[(long)l * 2048 + 1023 - l + j];
    float v = (j <= l) ? fmaxf(run, 0.f) : 0.f;
    wr[(long)l * 1024 + j] = (__bf16)v;
  }
}

// Row sums of wrelu (zeros above diagonal already stored): one wave per row.
__global__ void rowsum_kernel(const __bf16* __restrict__ wrelu, float* __restrict__ rowsum) {
  int row = blockIdx.x * 4 + (threadIdx.x >> 6);
  int l = threadIdx.x & 63;
  const __bf16* wr = wrelu + (long)row * 1024;
  bf16x8 a = *(const bf16x8*)&wr[l * 8];
  bf16x8 b = *(const bf16x8*)&wr[512 + l * 8];
  float s = 0.f;
#pragma unroll
  for (int t = 0; t < 8; ++t) s += (float)a[t] + (float)b[t];
#pragma unroll
  for (int off = 32; off; off >>= 1) s += __shfl_down(s, off);
  if (l == 0) rowsum[row] = s;
}

// ---------------------------------------------------------------------------
// Exact f32 recompute of rows l<32 (sign-flip hazard region). One block per b.
__global__ __launch_bounds__(1024) void small_fix(
    const float* __restrict__ x, const float* __restrict__ g2t,
    __bf16* __restrict__ wrelu, float* __restrict__ rowsum) {
  int b = blockIdx.x;
  int tid = threadIdx.x;
  __shared__ float S[32][33];
  {
    int m = tid >> 5, j = tid & 31;
    const float4* xr = (const float4*)(x + ((long)b * 1024 + m) * 512);
    const float4* gr = (const float4*)(g2t + (long)(31 - m + j) * 512);
    float s = 0.f;
    for (int t = 0; t < 128; ++t) {
      float4 a = xr[t], c = gr[t];
      s += a.x * c.x + a.y * c.y + a.z * c.z + a.w * c.w;
    }
    S[m][j] = s;
  }
  __syncthreads();
  if (tid < 32) { // cumsum over m for column j=tid
    int j = tid;
    float run = 0.f;
    for (int m = 0; m < 32; ++m) { run += S[m][j]; S[m][j] = run; }
  }
  __syncthreads();
  if (tid < 32) { // row l=tid: relu/tril, exact rowsum, overwrite
    int l = tid;
    float rs = 0.f;
    for (int j = 0; j <= l; ++j) rs += fmaxf(S[l][j], 0.f);
    rowsum[b * 1024 + l] = rs;
    __bf16* wr = wrelu + ((long)b * 1024 + l) * 1024;
    for (int j = 0; j < 32; ++j) {
      float v = (j <= l) ? fmaxf(S[l][j], 0.f) : 0.f;
      wr[j] = (__bf16)v;
    }
  }
}

// ---------------------------------------------------------------------------
extern "C" void kernel_launch(void* const* d_in, const int* in_sizes, int n_in,
                              void* d_out, int out_size, void* d_ws, size_t ws_size,
                              hipStream_t stream) {
  const float* x   = (const float*)d_in[0];
  const float* gen = (const float*)d_in[1];
  const float* Wq  = (const float*)d_in[2];
  const float* Wv  = (const float*)d_in[3];
  const float* Wc  = (const float*)d_in[4];

  char* ws = (char*)d_ws;
  __bf16* xb    = (__bf16*)(ws + 0L);
  __bf16* qb    = (__bf16*)(ws + 16777216L);
  __bf16* vT    = (__bf16*)(ws + 33554432L);
  __bf16* outn  = (__bf16*)(ws + 50331648L);
  __bf16* wfull = (__bf16*)(ws + 67108864L);
  __bf16* wrelu = (__bf16*)(ws + 134217728L);
  __bf16* genT  = (__bf16*)(ws + 167772160L);
  __bf16* wqb   = (__bf16*)(ws + 169869312L);
  __bf16* wvb   = (__bf16*)(ws + 170393600L);
  __bf16* wcb   = (__bf16*)(ws + 170917888L);
  float*  g2t   = (float*)(ws + 171442176L);
  // csum/rsum overlay the qb region (qb is dead after the w_full GEMM)
  float*  csum  = (float*)(ws + 16777216L);            // 1 MiB (16*16*1024 f32)
  float*  rsum  = (float*)(ws + 16777216L + 2097152L); // 64 KiB

  // conversions
  f2bf_kernel<<<8192, 256, 0, stream>>>(x, xb, 2097152);
  f2bf_kernel<<<256, 256, 0, stream>>>(Wq, wqb, 65536);
  f2bf_kernel<<<256, 256, 0, stream>>>(Wv, wvb, 65536);
  f2bf_kernel<<<256, 256, 0, stream>>>(Wc, wcb, 65536);
  genT_kernel<<<2048, 256, 0, stream>>>(gen, genT);
  g2t_kernel<<<63, 256, 0, stream>>>(Wq, gen, g2t);

  // q = x@Wq^T ; vT = (x@Wv^T)^T per batch ; w_full = q@genT^T (trapezoid band)
  gemm_bt<1><<<dim3(4, 128, 1), 256, 0, stream>>>(xb, wqb, qb, nullptr, 512, 512, 0, 0, 0, 0);
  gemm_bt<2><<<dim3(4, 128, 1), 256, 0, stream>>>(xb, wvb, vT, nullptr, 512, 512, 0, 0, 0, 0);
  gemm_bt<1, true><<<dim3(9, 128, 1), 256, 0, stream>>>(qb, genT, wfull, nullptr, 2048, 512, 0, 0, 0, 0);

  // gather + cumsum + relu/tril + rowsum
  chunk_sums<<<dim3(4, 16, 16), 256, 0, stream>>>(wfull, csum);
  scan_kernel<<<64, 256, 0, stream>>>(csum);
  cumsum_relu<<<dim3(4, 16, 16), 256, 0, stream>>>(wfull, csum, wrelu);
  rowsum_kernel<<<4096, 256, 0, stream>>>(wrelu, rsum);
  small_fix<<<16, 1024, 0, stream>>>(x, g2t, wrelu, rsum);

  // OUT = normalize(Wrelu) @ v  (batched), then Y = OUT @ Wc^T -> f32 d_out
  gemm_bt<3><<<dim3(4, 8, 16), 256, 0, stream>>>(wrelu, vT, outn, rsum, 512, 1024,
                                                 1024L * 1024, 512L * 1024, 512L * 1024, 1024);
  gemm_bt<0><<<dim3(4, 128, 1), 256, 0, stream>>>(outn, wcb, d_out, nullptr, 512, 512, 0, 0, 0, 0);
}

// Round 3
// 226.348 us; speedup vs baseline: 2.0944x; 1.3006x over previous
//
#include <hip/hip_runtime.h>
#include <hip/hip_bf16.h>

typedef __attribute__((ext_vector_type(8))) __bf16 bf16x8;
typedef __attribute__((ext_vector_type(4))) __bf16 bf16x4;
typedef __attribute__((ext_vector_type(4))) float  f32x4;

// ---------------------------------------------------------------------------
// async global->LDS, 16B per lane. LDS dest must be wave-uniform base.
__device__ __forceinline__ void gl_lds16(const __bf16* g, __bf16* l) {
  __builtin_amdgcn_global_load_lds(
      (const __attribute__((address_space(1))) void*)g,
      (__attribute__((address_space(3))) void*)l,
      16, 0, 0);
}

// ---------------------------------------------------------------------------
// f32 -> bf16 conversion, float4 vectorized
__global__ void f2bf_kernel(const float* __restrict__ in, __bf16* __restrict__ out, int n4) {
  int i = blockIdx.x * blockDim.x + threadIdx.x;
  if (i >= n4) return;
  float4 v = ((const float4*)in)[i];
  bf16x4 o;
  o[0] = (__bf16)v.x; o[1] = (__bf16)v.y; o[2] = (__bf16)v.z; o[3] = (__bf16)v.w;
  *(bf16x4*)(out + 4L * i) = o;
}

// gen (512 x 2047) f32 -> genT (2048 x 512) bf16, row 2047 zero-padded
__global__ void genT_kernel(const float* __restrict__ gen, __bf16* __restrict__ genT) {
  int i = blockIdx.x; // 0..2047
  for (int d = threadIdx.x; d < 512; d += blockDim.x) {
    float v = (i < 2047) ? gen[(long)d * 2047 + i] : 0.f;
    genT[(long)i * 512 + d] = (__bf16)v;
  }
}

// G2T[i][k] = sum_d Wq[d][k] * gen[d][992+i],  i in [0,63)  (f32 exact path)
__global__ void g2t_kernel(const float* __restrict__ Wq, const float* __restrict__ gen,
                           float* __restrict__ g2t) {
  int i = blockIdx.x;   // 0..62
  int k = threadIdx.x;  // 0..255
  float a0 = 0.f, a1 = 0.f;
  for (int d = 0; d < 512; ++d) {
    float g = gen[(long)d * 2047 + 992 + i];
    a0 += Wq[(long)d * 512 + k] * g;
    a1 += Wq[(long)d * 512 + k + 256] * g;
  }
  g2t[(long)i * 512 + k] = a0;
  g2t[(long)i * 512 + k + 256] = a1;
}

// ---------------------------------------------------------------------------
// bf16 GEMM, C = A @ B^T.  A: (M x K) row-major, B stored (N x K) row-major.
// 128x128 tile, BK=32, 4 waves, mfma_f32_16x16x32_bf16 (m97 structure).
// MODE 0: store f32 C (ldc=N).      MODE 1: store bf16 C (ldc=N).
// MODE 2: store bf16 C^T per batch-of-1024-rows: C[(m>>10)*512+n][m&1023] (vT).
// MODE 3: bf16 C scaled per-row by 1/(aux[row]+1e-8).
// DIAG: trapezoid n-tile mapping for the w_full band (9 n-tiles per m-tile).
// TRIL: A is lower-triangular in K (A[m,k]=0 for k>m) -> K-loop ends at m0+128.
template <int MODE, bool DIAG = false, bool TRIL = false>
__global__ __launch_bounds__(256) void gemm_bt(
    const __bf16* __restrict__ A, const __bf16* __restrict__ B, void* __restrict__ Cv,
    const float* __restrict__ aux, int N, int K, long sA, long sB, long sC, int sAux) {
  __shared__ __bf16 As[128 * 32];
  __shared__ __bf16 Bs[128 * 32];
  const int tid = threadIdx.x;
  const int w = tid >> 6, l = tid & 63;
  const int m0 = blockIdx.y * 128;
  const int n0 = DIAG ? (7 - (int)(blockIdx.y & 7) + (int)blockIdx.x) * 128
                      : blockIdx.x * 128;
  const int bz = blockIdx.z;
  const __bf16* Ab = A + (long)bz * sA;
  const __bf16* Bb = B + (long)bz * sB;

  const int srow = w * 16 + (l >> 2);   // staging row within 64-row half
  const int scol = (l & 3) * 8;         // staging col (8 bf16 = 16B)
  const int wr = (w >> 1) * 64, wc = (w & 1) * 64;
  const int fr = l & 15, fk = (l >> 4) * 8;

  f32x4 acc[4][4] = {};

  const int KM = TRIL ? min(K, m0 + 128) : K;
  for (int k0 = 0; k0 < KM; k0 += 32) {
    __syncthreads();
    gl_lds16(Ab + (long)(m0 + srow) * K + (k0 + scol),      &As[(w * 16) * 32]);
    gl_lds16(Ab + (long)(m0 + 64 + srow) * K + (k0 + scol), &As[(64 + w * 16) * 32]);
    gl_lds16(Bb + (long)(n0 + srow) * K + (k0 + scol),      &Bs[(w * 16) * 32]);
    gl_lds16(Bb + (long)(n0 + 64 + srow) * K + (k0 + scol), &Bs[(64 + w * 16) * 32]);
    __syncthreads();

    bf16x8 af[4], bg[4];
#pragma unroll
    for (int i = 0; i < 4; ++i) af[i] = *(const bf16x8*)&As[(wr + i * 16 + fr) * 32 + fk];
#pragma unroll
    for (int j = 0; j < 4; ++j) bg[j] = *(const bf16x8*)&Bs[(wc + j * 16 + fr) * 32 + fk];
#pragma unroll
    for (int i = 0; i < 4; ++i)
#pragma unroll
      for (int j = 0; j < 4; ++j)
        acc[i][j] = __builtin_amdgcn_mfma_f32_16x16x32_bf16(af[i], bg[j], acc[i][j], 0, 0, 0);
  }

  const int rbase = m0 + wr + ((l >> 4) << 2);
  const int cbase = n0 + wc + fr;

  if constexpr (MODE == 0) {
    float* C = (float*)Cv + (long)bz * sC;
#pragma unroll
    for (int i = 0; i < 4; ++i)
#pragma unroll
      for (int r = 0; r < 4; ++r) {
        long row = rbase + i * 16 + r;
#pragma unroll
        for (int j = 0; j < 4; ++j) C[row * N + cbase + j * 16] = acc[i][j][r];
      }
  } else if constexpr (MODE == 1) {
    __bf16* C = (__bf16*)Cv + (long)bz * sC;
#pragma unroll
    for (int i = 0; i < 4; ++i)
#pragma unroll
      for (int r = 0; r < 4; ++r) {
        long row = rbase + i * 16 + r;
#pragma unroll
        for (int j = 0; j < 4; ++j) C[row * N + cbase + j * 16] = (__bf16)acc[i][j][r];
      }
  } else if constexpr (MODE == 2) {
    __bf16* C = (__bf16*)Cv;
#pragma unroll
    for (int i = 0; i < 4; ++i) {
      int gm = rbase + i * 16;
      int bt = gm >> 10, lloc = gm & 1023;
#pragma unroll
      for (int j = 0; j < 4; ++j) {
        bf16x4 pk;
        pk[0] = (__bf16)acc[i][j][0]; pk[1] = (__bf16)acc[i][j][1];
        pk[2] = (__bf16)acc[i][j][2]; pk[3] = (__bf16)acc[i][j][3];
        *(bf16x4*)&C[((long)bt * 512 + cbase + j * 16) * 1024 + lloc] = pk;
      }
    }
  } else { // MODE 3
    __bf16* C = (__bf16*)Cv + (long)bz * sC;
    const float* ax = aux + (long)bz * sAux;
#pragma unroll
    for (int i = 0; i < 4; ++i)
#pragma unroll
      for (int r = 0; r < 4; ++r) {
        long row = rbase + i * 16 + r;
        float sc = 1.f / (ax[row] + 1e-8f);
#pragma unroll
        for (int j = 0; j < 4; ++j) C[row * N + cbase + j * 16] = (__bf16)(acc[i][j][r] * sc);
      }
  }
}

// ---------------------------------------------------------------------------
// S[b,l,j] = w_full[b,l,1023-l+j].  Two-level cumsum over l, 32 chunks of 32.
// Phase 1: per-chunk column sums.
__global__ void chunk_sums(const __bf16* __restrict__ wfull, float* __restrict__ csum) {
  int j = blockIdx.x * 256 + threadIdx.x;
  int c = blockIdx.y, b = blockIdx.z;
  const __bf16* base = wfull + (long)b * 1024 * 2048;
  float acc = 0.f;
  int l0 = c * 32;
  for (int l = l0; l < l0 + 32; ++l)
    acc += (float)base[(long)l * 2048 + 1023 - l + j];
  csum[((long)(b * 32 + c) << 10) + j] = acc;
}

// Phase 2: register exclusive scan over the 32 chunks per (b,j)
__global__ void scan_kernel(float* __restrict__ csum) {
  int idx = blockIdx.x * 256 + threadIdx.x; // 0..16383
  int b = idx >> 10, j = idx & 1023;
  long base = ((long)b * 32 << 10) + j;
  float v[32];
#pragma unroll
  for (int c = 0; c < 32; ++c) v[c] = csum[base + ((long)c << 10)];
  float s = 0.f;
#pragma unroll
  for (int c = 0; c < 32; ++c) { float t = v[c]; csum[base + ((long)c << 10)] = s; s += t; }
}

// Phase 3: walk chunk with offset, relu+tril, store bf16 weights
__global__ void cumsum_relu(const __bf16* __restrict__ wfull, const float* __restrict__ csum,
                            __bf16* __restrict__ wrelu) {
  int j = blockIdx.x * 256 + threadIdx.x;
  int c = blockIdx.y, b = blockIdx.z;
  float run = csum[((long)(b * 32 + c) << 10) + j];
  const __bf16* base = wfull + (long)b * 1024 * 2048;
  __bf16* wr = wrelu + (long)b * 1024 * 1024;
  int l0 = c * 32;
  for (int l = l0; l < l0 + 32; ++l) {
    run += (float)base[(long)l * 2048 + 1023 - l + j];
    float v = (j <= l) ? fmaxf(run, 0.f) : 0.f;
    wr[(long)l * 1024 + j] = (__bf16)v;
  }
}

// Row sums of wrelu (zeros above diagonal already stored): one wave per row.
__global__ void rowsum_kernel(const __bf16* __restrict__ wrelu, float* __restrict__ rowsum) {
  int row = blockIdx.x * 4 + (threadIdx.x >> 6);
  int l = threadIdx.x & 63;
  const __bf16* wr = wrelu + (long)row * 1024;
  bf16x8 a = *(const bf16x8*)&wr[l * 8];
  bf16x8 b = *(const bf16x8*)&wr[512 + l * 8];
  float s = 0.f;
#pragma unroll
  for (int t = 0; t < 8; ++t) s += (float)a[t] + (float)b[t];
#pragma unroll
  for (int off = 32; off; off >>= 1) s += __shfl_down(s, off);
  if (l == 0) rowsum[row] = s;
}

// ---------------------------------------------------------------------------
// Exact f32 path for rows l<32 (sign-flip hazard region).
// Stage A: S[b,m,j] = x[b,m,:] . g2t[31-m+j,:]  -- one wave per dot product.
__global__ __launch_bounds__(256) void small_dots(
    const float* __restrict__ x, const float* __restrict__ g2t, float* __restrict__ S) {
  int gid = blockIdx.x * 4 + (threadIdx.x >> 6); // 0..16383
  int lane = threadIdx.x & 63;
  int b = gid >> 10, rem = gid & 1023, m = rem >> 5, j = rem & 31;
  const float4* xr = (const float4*)(x + ((long)b * 1024 + m) * 512);
  const float4* gr = (const float4*)(g2t + (long)(31 - m + j) * 512);
  float4 a0 = xr[lane * 2], a1 = xr[lane * 2 + 1];
  float4 c0 = gr[lane * 2], c1 = gr[lane * 2 + 1];
  float s = a0.x * c0.x + a0.y * c0.y + a0.z * c0.z + a0.w * c0.w
          + a1.x * c1.x + a1.y * c1.y + a1.z * c1.z + a1.w * c1.w;
#pragma unroll
  for (int off = 32; off; off >>= 1) s += __shfl_down(s, off);
  if (lane == 0) S[gid] = s;
}

// Stage B: per-b 32x32 scan + relu/tril + exact rowsum + overwrite wrelu.
__global__ __launch_bounds__(1024) void small_scan(
    const float* __restrict__ Sg, __bf16* __restrict__ wrelu, float* __restrict__ rowsum) {
  int b = blockIdx.x, tid = threadIdx.x;
  __shared__ float S[32][33];
  int m = tid >> 5, j = tid & 31;
  S[m][j] = Sg[b * 1024 + tid];
  __syncthreads();
  if (tid < 32) { // cumsum over m for column j=tid
    float run = 0.f;
    for (int mm = 0; mm < 32; ++mm) { run += S[mm][tid]; S[mm][tid] = run; }
  }
  __syncthreads();
  float v = (j <= m) ? fmaxf(S[m][j], 0.f) : 0.f;
  wrelu[((long)b * 1024 + m) * 1024 + j] = (__bf16)v;
  float rs = v;
#pragma unroll
  for (int off = 16; off; off >>= 1) rs += __shfl_down(rs, off, 32);
  if (j == 0) rowsum[b * 1024 + m] = rs;
}

// ---------------------------------------------------------------------------
extern "C" void kernel_launch(void* const* d_in, const int* in_sizes, int n_in,
                              void* d_out, int out_size, void* d_ws, size_t ws_size,
                              hipStream_t stream) {
  const float* x   = (const float*)d_in[0];
  const float* gen = (const float*)d_in[1];
  const float* Wq  = (const float*)d_in[2];
  const float* Wv  = (const float*)d_in[3];
  const float* Wc  = (const float*)d_in[4];

  char* ws = (char*)d_ws;
  __bf16* xb    = (__bf16*)(ws + 0L);
  __bf16* qb    = (__bf16*)(ws + 16777216L);
  __bf16* vT    = (__bf16*)(ws + 33554432L);
  __bf16* outn  = (__bf16*)(ws + 50331648L);
  __bf16* wfull = (__bf16*)(ws + 67108864L);
  __bf16* wrelu = (__bf16*)(ws + 134217728L);
  __bf16* genT  = (__bf16*)(ws + 167772160L);
  __bf16* wqb   = (__bf16*)(ws + 169869312L);
  __bf16* wvb   = (__bf16*)(ws + 170393600L);
  __bf16* wcb   = (__bf16*)(ws + 170917888L);
  float*  g2t   = (float*)(ws + 171442176L);
  // csum/rsum/Sbuf overlay the qb region (qb is dead after the w_full GEMM)
  float*  csum  = (float*)(ws + 16777216L);            // 2 MiB (16*32*1024 f32)
  float*  rsum  = (float*)(ws + 16777216L + 2097152L); // 64 KiB
  float*  Sbuf  = (float*)(ws + 16777216L + 2162688L); // 64 KiB

  // conversions
  f2bf_kernel<<<8192, 256, 0, stream>>>(x, xb, 2097152);
  f2bf_kernel<<<256, 256, 0, stream>>>(Wq, wqb, 65536);
  f2bf_kernel<<<256, 256, 0, stream>>>(Wv, wvb, 65536);
  f2bf_kernel<<<256, 256, 0, stream>>>(Wc, wcb, 65536);
  genT_kernel<<<2048, 256, 0, stream>>>(gen, genT);
  g2t_kernel<<<63, 256, 0, stream>>>(Wq, gen, g2t);

  // q = x@Wq^T ; vT = (x@Wv^T)^T per batch ; w_full = q@genT^T (trapezoid band)
  gemm_bt<1><<<dim3(4, 128, 1), 256, 0, stream>>>(xb, wqb, qb, nullptr, 512, 512, 0, 0, 0, 0);
  gemm_bt<2><<<dim3(4, 128, 1), 256, 0, stream>>>(xb, wvb, vT, nullptr, 512, 512, 0, 0, 0, 0);
  gemm_bt<1, true><<<dim3(9, 128, 1), 256, 0, stream>>>(qb, genT, wfull, nullptr, 2048, 512, 0, 0, 0, 0);

  // gather + cumsum + relu/tril + rowsum
  chunk_sums<<<dim3(4, 32, 16), 256, 0, stream>>>(wfull, csum);
  scan_kernel<<<64, 256, 0, stream>>>(csum);
  cumsum_relu<<<dim3(4, 32, 16), 256, 0, stream>>>(wfull, csum, wrelu);
  rowsum_kernel<<<4096, 256, 0, stream>>>(wrelu, rsum);

  // exact f32 fix for rows l<32
  small_dots<<<4096, 256, 0, stream>>>(x, g2t, Sbuf);
  small_scan<<<16, 1024, 0, stream>>>(Sbuf, wrelu, rsum);

  // OUT = normalize(Wrelu) @ v  (batched, triangular), then Y = OUT @ Wc^T -> f32 d_out
  gemm_bt<3, false, true><<<dim3(4, 8, 16), 256, 0, stream>>>(wrelu, vT, outn, rsum, 512, 1024,
                                                 1024L * 1024, 512L * 1024, 512L * 1024, 1024);
  gemm_bt<0><<<dim3(4, 128, 1), 256, 0, stream>>>(outn, wcb, d_out, nullptr, 512, 512, 0, 0, 0, 0);
}

// Round 4
// 197.439 us; speedup vs baseline: 2.4010x; 1.1464x over previous
//
#include <hip/hip_runtime.h>
#include <hip/hip_bf16.h>

typedef __attribute__((ext_vector_type(8))) __bf16 bf16x8;
typedef __attribute__((ext_vector_type(4))) __bf16 bf16x4;
typedef __attribute__((ext_vector_type(4))) float  f32x4;

// ---------------------------------------------------------------------------
// async global->LDS, 16B per lane. LDS dest must be wave-uniform base.
__device__ __forceinline__ void gl_lds16(const __bf16* g, __bf16* l) {
  __builtin_amdgcn_global_load_lds(
      (const __attribute__((address_space(1))) void*)g,
      (__attribute__((address_space(3))) void*)l,
      16, 0, 0);
}

// ---------------------------------------------------------------------------
// f32 -> bf16 conversion, float4 vectorized
__global__ void f2bf_kernel(const float* __restrict__ in, __bf16* __restrict__ out, int n4) {
  int i = blockIdx.x * blockDim.x + threadIdx.x;
  if (i >= n4) return;
  float4 v = ((const float4*)in)[i];
  bf16x4 o;
  o[0] = (__bf16)v.x; o[1] = (__bf16)v.y; o[2] = (__bf16)v.z; o[3] = (__bf16)v.w;
  *(bf16x4*)(out + 4L * i) = o;
}

// gen (512 x 2047) f32 -> genT (2048 x 512) bf16, row 2047 zero-padded
__global__ void genT_kernel(const float* __restrict__ gen, __bf16* __restrict__ genT) {
  int i = blockIdx.x; // 0..2047
  for (int d = threadIdx.x; d < 512; d += blockDim.x) {
    float v = (i < 2047) ? gen[(long)d * 2047 + i] : 0.f;
    genT[(long)i * 512 + d] = (__bf16)v;
  }
}

// ---------------------------------------------------------------------------
// g2t[i][k] = sum_d Wq[d][k] * gen[d][992+i],  i in [0,63)  (f32 exact path)
// Stage 1: partial sums over 8 d-chunks of 64.
__global__ void g2t_part(const float* __restrict__ Wq, const float* __restrict__ gen,
                         float* __restrict__ gp) {
  int i = blockIdx.x;   // 0..62
  int c = blockIdx.y;   // 0..7
  int k = threadIdx.x;  // 0..255
  int d0 = c * 64;
  float a0 = 0.f, a1 = 0.f;
#pragma unroll 8
  for (int t = 0; t < 64; ++t) {
    int d = d0 + t;
    float g = gen[(long)d * 2047 + 992 + i];
    a0 += Wq[(long)d * 512 + k] * g;
    a1 += Wq[(long)d * 512 + k + 256] * g;
  }
  long o = ((long)c * 63 + i) * 512;
  gp[o + k] = a0;
  gp[o + k + 256] = a1;
}

// Stage 2: reduce the 8 partials.
__global__ void g2t_reduce(const float* __restrict__ gp, float* __restrict__ g2t) {
  int idx = blockIdx.x * 256 + threadIdx.x; // 0..32255
  if (idx >= 63 * 512) return;
  float s = 0.f;
#pragma unroll
  for (int c = 0; c < 8; ++c) s += gp[(long)c * 63 * 512 + idx];
  g2t[idx] = s;
}

// ---------------------------------------------------------------------------
// bf16 GEMM, C = A @ B^T.  A: (M x K) row-major, B stored (N x K) row-major.
// 128x128 tile, BK=32, 4 waves, mfma_f32_16x16x32_bf16 (m97 structure).
// MODE 0: store f32 C (ldc=N).      MODE 1: store bf16 C (ldc=N).
// MODE 2: store bf16 C^T per batch-of-1024-rows: C[(m>>10)*512+n][m&1023] (vT).
// MODE 3: bf16 C scaled per-row by 1/(aux[row]+1e-8).
// DIAG: trapezoid n-tile mapping for the w_full band (9 n-tiles per m-tile).
// TRIL: A is lower-triangular in K (A[m,k]=0 for k>m) -> K-loop ends at m0+128.
template <int MODE, bool DIAG = false, bool TRIL = false>
__global__ __launch_bounds__(256) void gemm_bt(
    const __bf16* __restrict__ A, const __bf16* __restrict__ B, void* __restrict__ Cv,
    const float* __restrict__ aux, int N, int K, long sA, long sB, long sC, int sAux) {
  __shared__ __bf16 As[128 * 32];
  __shared__ __bf16 Bs[128 * 32];
  const int tid = threadIdx.x;
  const int w = tid >> 6, l = tid & 63;
  const int m0 = blockIdx.y * 128;
  const int n0 = DIAG ? (7 - (int)(blockIdx.y & 7) + (int)blockIdx.x) * 128
                      : blockIdx.x * 128;
  const int bz = blockIdx.z;
  const __bf16* Ab = A + (long)bz * sA;
  const __bf16* Bb = B + (long)bz * sB;

  const int srow = w * 16 + (l >> 2);   // staging row within 64-row half
  const int scol = (l & 3) * 8;         // staging col (8 bf16 = 16B)
  const int wr = (w >> 1) * 64, wc = (w & 1) * 64;
  const int fr = l & 15, fk = (l >> 4) * 8;

  f32x4 acc[4][4] = {};

  const int KM = TRIL ? min(K, m0 + 128) : K;
  for (int k0 = 0; k0 < KM; k0 += 32) {
    __syncthreads();
    gl_lds16(Ab + (long)(m0 + srow) * K + (k0 + scol),      &As[(w * 16) * 32]);
    gl_lds16(Ab + (long)(m0 + 64 + srow) * K + (k0 + scol), &As[(64 + w * 16) * 32]);
    gl_lds16(Bb + (long)(n0 + srow) * K + (k0 + scol),      &Bs[(w * 16) * 32]);
    gl_lds16(Bb + (long)(n0 + 64 + srow) * K + (k0 + scol), &Bs[(64 + w * 16) * 32]);
    __syncthreads();

    bf16x8 af[4], bg[4];
#pragma unroll
    for (int i = 0; i < 4; ++i) af[i] = *(const bf16x8*)&As[(wr + i * 16 + fr) * 32 + fk];
#pragma unroll
    for (int j = 0; j < 4; ++j) bg[j] = *(const bf16x8*)&Bs[(wc + j * 16 + fr) * 32 + fk];
#pragma unroll
    for (int i = 0; i < 4; ++i)
#pragma unroll
      for (int j = 0; j < 4; ++j)
        acc[i][j] = __builtin_amdgcn_mfma_f32_16x16x32_bf16(af[i], bg[j], acc[i][j], 0, 0, 0);
  }

  const int rbase = m0 + wr + ((l >> 4) << 2);
  const int cbase = n0 + wc + fr;

  if constexpr (MODE == 0) {
    float* C = (float*)Cv + (long)bz * sC;
#pragma unroll
    for (int i = 0; i < 4; ++i)
#pragma unroll
      for (int r = 0; r < 4; ++r) {
        long row = rbase + i * 16 + r;
#pragma unroll
        for (int j = 0; j < 4; ++j) C[row * N + cbase + j * 16] = acc[i][j][r];
      }
  } else if constexpr (MODE == 1) {
    __bf16* C = (__bf16*)Cv + (long)bz * sC;
#pragma unroll
    for (int i = 0; i < 4; ++i)
#pragma unroll
      for (int r = 0; r < 4; ++r) {
        long row = rbase + i * 16 + r;
#pragma unroll
        for (int j = 0; j < 4; ++j) C[row * N + cbase + j * 16] = (__bf16)acc[i][j][r];
      }
  } else if constexpr (MODE == 2) {
    __bf16* C = (__bf16*)Cv;
#pragma unroll
    for (int i = 0; i < 4; ++i) {
      int gm = rbase + i * 16;
      int bt = gm >> 10, lloc = gm & 1023;
#pragma unroll
      for (int j = 0; j < 4; ++j) {
        bf16x4 pk;
        pk[0] = (__bf16)acc[i][j][0]; pk[1] = (__bf16)acc[i][j][1];
        pk[2] = (__bf16)acc[i][j][2]; pk[3] = (__bf16)acc[i][j][3];
        *(bf16x4*)&C[((long)bt * 512 + cbase + j * 16) * 1024 + lloc] = pk;
      }
    }
  } else { // MODE 3
    __bf16* C = (__bf16*)Cv + (long)bz * sC;
    const float* ax = aux + (long)bz * sAux;
#pragma unroll
    for (int i = 0; i < 4; ++i)
#pragma unroll
      for (int r = 0; r < 4; ++r) {
        long row = rbase + i * 16 + r;
        float sc = 1.f / (ax[row] + 1e-8f);
#pragma unroll
        for (int j = 0; j < 4; ++j) C[row * N + cbase + j * 16] = (__bf16)(acc[i][j][r] * sc);
      }
  }
}

// ---------------------------------------------------------------------------
// S[b,l,j] = w_full[b,l,1023-l+j].  Two-level cumsum over l, 32 chunks of 32.
// Phase 1: per-chunk column sums.
__global__ void chunk_sums(const __bf16* __restrict__ wfull, float* __restrict__ csum) {
  int j = blockIdx.x * 256 + threadIdx.x;
  int c = blockIdx.y, b = blockIdx.z;
  const __bf16* base = wfull + (long)b * 1024 * 2048;
  float acc = 0.f;
  int l0 = c * 32;
  for (int l = l0; l < l0 + 32; ++l)
    acc += (float)base[(long)l * 2048 + 1023 - l + j];
  csum[((long)(b * 32 + c) << 10) + j] = acc;
}

// Phase 2: register exclusive scan over the 32 chunks per (b,j)
__global__ void scan_kernel(float* __restrict__ csum) {
  int idx = blockIdx.x * 256 + threadIdx.x; // 0..16383
  int b = idx >> 10, j = idx & 1023;
  long base = ((long)b * 32 << 10) + j;
  float v[32];
#pragma unroll
  for (int c = 0; c < 32; ++c) v[c] = csum[base + ((long)c << 10)];
  float s = 0.f;
#pragma unroll
  for (int c = 0; c < 32; ++c) { float t = v[c]; csum[base + ((long)c << 10)] = s; s += t; }
}

// Phase 3: walk chunk with offset, relu+tril, store bf16 weights
__global__ void cumsum_relu(const __bf16* __restrict__ wfull, const float* __restrict__ csum,
                            __bf16* __restrict__ wrelu) {
  int j = blockIdx.x * 256 + threadIdx.x;
  int c = blockIdx.y, b = blockIdx.z;
  float run = csum[((long)(b * 32 + c) << 10) + j];
  const __bf16* base = wfull + (long)b * 1024 * 2048;
  __bf16* wr = wrelu + (long)b * 1024 * 1024;
  int l0 = c * 32;
  for (int l = l0; l < l0 + 32; ++l) {
    run += (float)base[(long)l * 2048 + 1023 - l + j];
    float v = (j <= l) ? fmaxf(run, 0.f) : 0.f;
    wr[(long)l * 1024 + j] = (__bf16)v;
  }
}

// Row sums of wrelu (zeros above diagonal already stored): one wave per row.
__global__ void rowsum_kernel(const __bf16* __restrict__ wrelu, float* __restrict__ rowsum) {
  int row = blockIdx.x * 4 + (threadIdx.x >> 6);
  int l = threadIdx.x & 63;
  const __bf16* wr = wrelu + (long)row * 1024;
  bf16x8 a = *(const bf16x8*)&wr[l * 8];
  bf16x8 b = *(const bf16x8*)&wr[512 + l * 8];
  float s = 0.f;
#pragma unroll
  for (int t = 0; t < 8; ++t) s += (float)a[t] + (float)b[t];
#pragma unroll
  for (int off = 32; off; off >>= 1) s += __shfl_down(s, off);
  if (l == 0) rowsum[row] = s;
}

// ---------------------------------------------------------------------------
// Exact f32 path for rows l<32 (sign-flip hazard region).
// Stage A: S[b,m,j] = x[b,m,:] . g2t[31-m+j,:]  -- one wave per dot product.
__global__ __launch_bounds__(256) void small_dots(
    const float* __restrict__ x, const float* __restrict__ g2t, float* __restrict__ S) {
  int gid = blockIdx.x * 4 + (threadIdx.x >> 6); // 0..16383
  int lane = threadIdx.x & 63;
  int b = gid >> 10, rem = gid & 1023, m = rem >> 5, j = rem & 31;
  const float4* xr = (const float4*)(x + ((long)b * 1024 + m) * 512);
  const float4* gr = (const float4*)(g2t + (long)(31 - m + j) * 512);
  float4 a0 = xr[lane * 2], a1 = xr[lane * 2 + 1];
  float4 c0 = gr[lane * 2], c1 = gr[lane * 2 + 1];
  float s = a0.x * c0.x + a0.y * c0.y + a0.z * c0.z + a0.w * c0.w
          + a1.x * c1.x + a1.y * c1.y + a1.z * c1.z + a1.w * c1.w;
#pragma unroll
  for (int off = 32; off; off >>= 1) s += __shfl_down(s, off);
  if (lane == 0) S[gid] = s;
}

// Stage B: per-b 32x32 scan + relu/tril + exact rowsum + overwrite wrelu.
__global__ __launch_bounds__(1024) void small_scan(
    const float* __restrict__ Sg, __bf16* __restrict__ wrelu, float* __restrict__ rowsum) {
  int b = blockIdx.x, tid = threadIdx.x;
  __shared__ float S[32][33];
  int m = tid >> 5, j = tid & 31;
  S[m][j] = Sg[b * 1024 + tid];
  __syncthreads();
  if (tid < 32) { // cumsum over m for column j=tid
    float run = 0.f;
    for (int mm = 0; mm < 32; ++mm) { run += S[mm][tid]; S[mm][tid] = run; }
  }
  __syncthreads();
  float v = (j <= m) ? fmaxf(S[m][j], 0.f) : 0.f;
  wrelu[((long)b * 1024 + m) * 1024 + j] = (__bf16)v;
  float rs = v;
#pragma unroll
  for (int off = 16; off; off >>= 1) rs += __shfl_down(rs, off, 32);
  if (j == 0) rowsum[b * 1024 + m] = rs;
}

// ---------------------------------------------------------------------------
extern "C" void kernel_launch(void* const* d_in, const int* in_sizes, int n_in,
                              void* d_out, int out_size, void* d_ws, size_t ws_size,
                              hipStream_t stream) {
  const float* x   = (const float*)d_in[0];
  const float* gen = (const float*)d_in[1];
  const float* Wq  = (const float*)d_in[2];
  const float* Wv  = (const float*)d_in[3];
  const float* Wc  = (const float*)d_in[4];

  char* ws = (char*)d_ws;
  __bf16* xb    = (__bf16*)(ws + 0L);
  __bf16* qb    = (__bf16*)(ws + 16777216L);
  __bf16* vT    = (__bf16*)(ws + 33554432L);
  __bf16* outn  = (__bf16*)(ws + 50331648L);
  __bf16* wfull = (__bf16*)(ws + 67108864L);
  __bf16* wrelu = (__bf16*)(ws + 134217728L);
  __bf16* genT  = (__bf16*)(ws + 167772160L);
  __bf16* wqb   = (__bf16*)(ws + 169869312L);
  __bf16* wvb   = (__bf16*)(ws + 170393600L);
  __bf16* wcb   = (__bf16*)(ws + 170917888L);
  float*  g2t   = (float*)(ws + 171442176L);
  // csum/rsum/Sbuf overlay the qb region (qb is dead after the w_full GEMM)
  float*  csum  = (float*)(ws + 16777216L);            // 2 MiB (16*32*1024 f32)
  float*  rsum  = (float*)(ws + 16777216L + 2097152L); // 64 KiB
  float*  Sbuf  = (float*)(ws + 16777216L + 2162688L); // 64 KiB
  // g2t partials overlay the outn region (outn written only by the late MODE-3 GEMM)
  float*  gp    = (float*)(ws + 50331648L);            // 8*63*512*4 = 1 MiB

  // conversions
  f2bf_kernel<<<8192, 256, 0, stream>>>(x, xb, 2097152);
  f2bf_kernel<<<256, 256, 0, stream>>>(Wq, wqb, 65536);
  f2bf_kernel<<<256, 256, 0, stream>>>(Wv, wvb, 65536);
  f2bf_kernel<<<256, 256, 0, stream>>>(Wc, wcb, 65536);
  genT_kernel<<<2048, 256, 0, stream>>>(gen, genT);
  g2t_part<<<dim3(63, 8), 256, 0, stream>>>(Wq, gen, gp);
  g2t_reduce<<<126, 256, 0, stream>>>(gp, g2t);

  // q = x@Wq^T ; vT = (x@Wv^T)^T per batch ; w_full = q@genT^T (trapezoid band)
  gemm_bt<1><<<dim3(4, 128, 1), 256, 0, stream>>>(xb, wqb, qb, nullptr, 512, 512, 0, 0, 0, 0);
  gemm_bt<2><<<dim3(4, 128, 1), 256, 0, stream>>>(xb, wvb, vT, nullptr, 512, 512, 0, 0, 0, 0);
  gemm_bt<1, true><<<dim3(9, 128, 1), 256, 0, stream>>>(qb, genT, wfull, nullptr, 2048, 512, 0, 0, 0, 0);

  // gather + cumsum + relu/tril + rowsum
  chunk_sums<<<dim3(4, 32, 16), 256, 0, stream>>>(wfull, csum);
  scan_kernel<<<64, 256, 0, stream>>>(csum);
  cumsum_relu<<<dim3(4, 32, 16), 256, 0, stream>>>(wfull, csum, wrelu);
  rowsum_kernel<<<4096, 256, 0, stream>>>(wrelu, rsum);

  // exact f32 fix for rows l<32
  small_dots<<<4096, 256, 0, stream>>>(x, g2t, Sbuf);
  small_scan<<<16, 1024, 0, stream>>>(Sbuf, wrelu, rsum);

  // OUT = normalize(Wrelu) @ v  (batched, triangular), then Y = OUT @ Wc^T -> f32 d_out
  gemm_bt<3, false, true><<<dim3(4, 8, 16), 256, 0, stream>>>(wrelu, vT, outn, rsum, 512, 1024,
                                                 1024L * 1024, 512L * 1024, 512L * 1024, 1024);
  gemm_bt<0><<<dim3(4, 128, 1), 256, 0, stream>>>(outn, wcb, d_out, nullptr, 512, 512, 0, 0, 0, 0);
}

// Round 5
// 187.213 us; speedup vs baseline: 2.5322x; 1.0546x over previous
//
#include <hip/hip_runtime.h>
#include <hip/hip_bf16.h>

typedef __attribute__((ext_vector_type(8))) __bf16 bf16x8;
typedef __attribute__((ext_vector_type(4))) __bf16 bf16x4;
typedef __attribute__((ext_vector_type(4))) float  f32x4;

// ---------------------------------------------------------------------------
// async global->LDS, 16B per lane. LDS dest must be wave-uniform base.
__device__ __forceinline__ void gl_lds16(const __bf16* g, __bf16* l) {
  __builtin_amdgcn_global_load_lds(
      (const __attribute__((address_space(1))) void*)g,
      (__attribute__((address_space(3))) void*)l,
      16, 0, 0);
}

// ---------------------------------------------------------------------------
// f32 -> bf16 conversion, float4 vectorized
__global__ void f2bf_kernel(const float* __restrict__ in, __bf16* __restrict__ out, int n4) {
  int i = blockIdx.x * blockDim.x + threadIdx.x;
  if (i >= n4) return;
  float4 v = ((const float4*)in)[i];
  bf16x4 o;
  o[0] = (__bf16)v.x; o[1] = (__bf16)v.y; o[2] = (__bf16)v.z; o[3] = (__bf16)v.w;
  *(bf16x4*)(out + 4L * i) = o;
}

// 512x512 f32 -> bf16 transposed (out[e][d] = in[d][e]), LDS-tiled.
__global__ void transpose_f2bf(const float* __restrict__ in, __bf16* __restrict__ out) {
  __shared__ float S[64][65];
  int tx = threadIdx.x & 63, ty = threadIdx.x >> 6; // 64 x 4
  int d0 = blockIdx.y * 64, e0 = blockIdx.x * 64;
#pragma unroll
  for (int i = 0; i < 16; ++i) {
    int di = i * 4 + ty;
    S[di][tx] = in[(long)(d0 + di) * 512 + e0 + tx];
  }
  __syncthreads();
#pragma unroll
  for (int i = 0; i < 16; ++i) {
    int ei = i * 4 + ty;
    out[(long)(e0 + ei) * 512 + d0 + tx] = (__bf16)S[tx][ei];
  }
}

// gen (512 x 2047) f32 -> genT (2048 x 512) bf16, row 2047 zero-padded
__global__ void genT_kernel(const float* __restrict__ gen, __bf16* __restrict__ genT) {
  int i = blockIdx.x; // 0..2047
  for (int d = threadIdx.x; d < 512; d += blockDim.x) {
    float v = (i < 2047) ? gen[(long)d * 2047 + i] : 0.f;
    genT[(long)i * 512 + d] = (__bf16)v;
  }
}

// ---------------------------------------------------------------------------
// g2t[i][k] = sum_d Wq[d][k] * gen[d][992+i],  i in [0,63)  (f32 exact path)
// Stage 1: partial sums over 8 d-chunks of 64.
__global__ void g2t_part(const float* __restrict__ Wq, const float* __restrict__ gen,
                         float* __restrict__ gp) {
  int i = blockIdx.x;   // 0..62
  int c = blockIdx.y;   // 0..7
  int k = threadIdx.x;  // 0..255
  int d0 = c * 64;
  float a0 = 0.f, a1 = 0.f;
#pragma unroll 8
  for (int t = 0; t < 64; ++t) {
    int d = d0 + t;
    float g = gen[(long)d * 2047 + 992 + i];
    a0 += Wq[(long)d * 512 + k] * g;
    a1 += Wq[(long)d * 512 + k + 256] * g;
  }
  long o = ((long)c * 63 + i) * 512;
  gp[o + k] = a0;
  gp[o + k + 256] = a1;
}

// Stage 2: reduce the 8 partials.
__global__ void g2t_reduce(const float* __restrict__ gp, float* __restrict__ g2t) {
  int idx = blockIdx.x * 256 + threadIdx.x; // 0..32255
  if (idx >= 63 * 512) return;
  float s = 0.f;
#pragma unroll
  for (int c = 0; c < 8; ++c) s += gp[(long)c * 63 * 512 + idx];
  g2t[idx] = s;
}

// ---------------------------------------------------------------------------
// bf16 GEMM, C = A @ B^T.  A: (M x K) row-major, B stored (N x K) row-major.
// 128x128 tile, BK=32, 4 waves, mfma_f32_16x16x32_bf16 (m97 structure).
// MODE 0: store f32 C (ldc=N).      MODE 1: store bf16 C (ldc=N).
// MODE 2: store bf16 C^T per batch-of-1024-rows: C[(m>>10)*512+n][m&1023] (vT).
// MODE 3: bf16 C scaled per-row by 1/(aux[row]+1e-8).
// MODE 4: f32 C scaled per-row by 1/(aux[row]+1e-8)  (direct d_out write).
// DIAG: trapezoid n-tile mapping for the w_full band (9 n-tiles per m-tile).
// TRIL: A is lower-triangular in K (A[m,k]=0 for k>m) -> K-loop ends at m0+128.
template <int MODE, bool DIAG = false, bool TRIL = false>
__global__ __launch_bounds__(256) void gemm_bt(
    const __bf16* __restrict__ A, const __bf16* __restrict__ B, void* __restrict__ Cv,
    const float* __restrict__ aux, int N, int K, long sA, long sB, long sC, int sAux) {
  __shared__ __bf16 As[128 * 32];
  __shared__ __bf16 Bs[128 * 32];
  const int tid = threadIdx.x;
  const int w = tid >> 6, l = tid & 63;
  const int m0 = blockIdx.y * 128;
  const int n0 = DIAG ? (7 - (int)(blockIdx.y & 7) + (int)blockIdx.x) * 128
                      : blockIdx.x * 128;
  const int bz = blockIdx.z;
  const __bf16* Ab = A + (long)bz * sA;
  const __bf16* Bb = B + (long)bz * sB;

  const int srow = w * 16 + (l >> 2);   // staging row within 64-row half
  const int scol = (l & 3) * 8;         // staging col (8 bf16 = 16B)
  const int wr = (w >> 1) * 64, wc = (w & 1) * 64;
  const int fr = l & 15, fk = (l >> 4) * 8;

  f32x4 acc[4][4] = {};

  const int KM = TRIL ? min(K, m0 + 128) : K;
  for (int k0 = 0; k0 < KM; k0 += 32) {
    __syncthreads();
    gl_lds16(Ab + (long)(m0 + srow) * K + (k0 + scol),      &As[(w * 16) * 32]);
    gl_lds16(Ab + (long)(m0 + 64 + srow) * K + (k0 + scol), &As[(64 + w * 16) * 32]);
    gl_lds16(Bb + (long)(n0 + srow) * K + (k0 + scol),      &Bs[(w * 16) * 32]);
    gl_lds16(Bb + (long)(n0 + 64 + srow) * K + (k0 + scol), &Bs[(64 + w * 16) * 32]);
    __syncthreads();

    bf16x8 af[4], bg[4];
#pragma unroll
    for (int i = 0; i < 4; ++i) af[i] = *(const bf16x8*)&As[(wr + i * 16 + fr) * 32 + fk];
#pragma unroll
    for (int j = 0; j < 4; ++j) bg[j] = *(const bf16x8*)&Bs[(wc + j * 16 + fr) * 32 + fk];
#pragma unroll
    for (int i = 0; i < 4; ++i)
#pragma unroll
      for (int j = 0; j < 4; ++j)
        acc[i][j] = __builtin_amdgcn_mfma_f32_16x16x32_bf16(af[i], bg[j], acc[i][j], 0, 0, 0);
  }

  const int rbase = m0 + wr + ((l >> 4) << 2);
  const int cbase = n0 + wc + fr;

  if constexpr (MODE == 0) {
    float* C = (float*)Cv + (long)bz * sC;
#pragma unroll
    for (int i = 0; i < 4; ++i)
#pragma unroll
      for (int r = 0; r < 4; ++r) {
        long row = rbase + i * 16 + r;
#pragma unroll
        for (int j = 0; j < 4; ++j) C[row * N + cbase + j * 16] = acc[i][j][r];
      }
  } else if constexpr (MODE == 1) {
    __bf16* C = (__bf16*)Cv + (long)bz * sC;
#pragma unroll
    for (int i = 0; i < 4; ++i)
#pragma unroll
      for (int r = 0; r < 4; ++r) {
        long row = rbase + i * 16 + r;
#pragma unroll
        for (int j = 0; j < 4; ++j) C[row * N + cbase + j * 16] = (__bf16)acc[i][j][r];
      }
  } else if constexpr (MODE == 2) {
    __bf16* C = (__bf16*)Cv;
#pragma unroll
    for (int i = 0; i < 4; ++i) {
      int gm = rbase + i * 16;
      int bt = gm >> 10, lloc = gm & 1023;
#pragma unroll
      for (int j = 0; j < 4; ++j) {
        bf16x4 pk;
        pk[0] = (__bf16)acc[i][j][0]; pk[1] = (__bf16)acc[i][j][1];
        pk[2] = (__bf16)acc[i][j][2]; pk[3] = (__bf16)acc[i][j][3];
        *(bf16x4*)&C[((long)bt * 512 + cbase + j * 16) * 1024 + lloc] = pk;
      }
    }
  } else if constexpr (MODE == 3) {
    __bf16* C = (__bf16*)Cv + (long)bz * sC;
    const float* ax = aux + (long)bz * sAux;
#pragma unroll
    for (int i = 0; i < 4; ++i)
#pragma unroll
      for (int r = 0; r < 4; ++r) {
        long row = rbase + i * 16 + r;
        float sc = 1.f / (ax[row] + 1e-8f);
#pragma unroll
        for (int j = 0; j < 4; ++j) C[row * N + cbase + j * 16] = (__bf16)(acc[i][j][r] * sc);
      }
  } else { // MODE 4
    float* C = (float*)Cv + (long)bz * sC;
    const float* ax = aux + (long)bz * sAux;
#pragma unroll
    for (int i = 0; i < 4; ++i)
#pragma unroll
      for (int r = 0; r < 4; ++r) {
        long row = rbase + i * 16 + r;
        float sc = 1.f / (ax[row] + 1e-8f);
#pragma unroll
        for (int j = 0; j < 4; ++j) C[row * N + cbase + j * 16] = acc[i][j][r] * sc;
      }
  }
}

// ---------------------------------------------------------------------------
// S[b,l,j] = w_full[b,l,1023-l+j].  Two-level cumsum over l, 32 chunks of 32.
// Phase 1: per-chunk column sums.
__global__ void chunk_sums(const __bf16* __restrict__ wfull, float* __restrict__ csum) {
  int j = blockIdx.x * 256 + threadIdx.x;
  int c = blockIdx.y, b = blockIdx.z;
  const __bf16* base = wfull + (long)b * 1024 * 2048;
  float acc = 0.f;
  int l0 = c * 32;
  for (int l = l0; l < l0 + 32; ++l)
    acc += (float)base[(long)l * 2048 + 1023 - l + j];
  csum[((long)(b * 32 + c) << 10) + j] = acc;
}

// Phase 2: register exclusive scan over the 32 chunks per (b,j)
__global__ void scan_kernel(float* __restrict__ csum) {
  int idx = blockIdx.x * 256 + threadIdx.x; // 0..16383
  int b = idx >> 10, j = idx & 1023;
  long base = ((long)b * 32 << 10) + j;
  float v[32];
#pragma unroll
  for (int c = 0; c < 32; ++c) v[c] = csum[base + ((long)c << 10)];
  float s = 0.f;
#pragma unroll
  for (int c = 0; c < 32; ++c) { float t = v[c]; csum[base + ((long)c << 10)] = s; s += t; }
}

// Phase 3: walk chunk with offset, relu+tril, store bf16 weights
__global__ void cumsum_relu(const __bf16* __restrict__ wfull, const float* __restrict__ csum,
                            __bf16* __restrict__ wrelu) {
  int j = blockIdx.x * 256 + threadIdx.x;
  int c = blockIdx.y, b = blockIdx.z;
  float run = csum[((long)(b * 32 + c) << 10) + j];
  const __bf16* base = wfull + (long)b * 1024 * 2048;
  __bf16* wr = wrelu + (long)b * 1024 * 1024;
  int l0 = c * 32;
  for (int l = l0; l < l0 + 32; ++l) {
    run += (float)base[(long)l * 2048 + 1023 - l + j];
    float v = (j <= l) ? fmaxf(run, 0.f) : 0.f;
    wr[(long)l * 1024 + j] = (__bf16)v;
  }
}

// Row sums of wrelu (zeros above diagonal already stored): one wave per row.
__global__ void rowsum_kernel(const __bf16* __restrict__ wrelu, float* __restrict__ rowsum) {
  int row = blockIdx.x * 4 + (threadIdx.x >> 6);
  int l = threadIdx.x & 63;
  const __bf16* wr = wrelu + (long)row * 1024;
  bf16x8 a = *(const bf16x8*)&wr[l * 8];
  bf16x8 b = *(const bf16x8*)&wr[512 + l * 8];
  float s = 0.f;
#pragma unroll
  for (int t = 0; t < 8; ++t) s += (float)a[t] + (float)b[t];
#pragma unroll
  for (int off = 32; off; off >>= 1) s += __shfl_down(s, off);
  if (l == 0) rowsum[row] = s;
}

// ---------------------------------------------------------------------------
// Exact f32 path for rows l<32 (sign-flip hazard region).
// Stage A: S[b,m,j] = x[b,m,:] . g2t[31-m+j,:]  -- one wave per dot product.
__global__ __launch_bounds__(256) void small_dots(
    const float* __restrict__ x, const float* __restrict__ g2t, float* __restrict__ S) {
  int gid = blockIdx.x * 4 + (threadIdx.x >> 6); // 0..16383
  int lane = threadIdx.x & 63;
  int b = gid >> 10, rem = gid & 1023, m = rem >> 5, j = rem & 31;
  const float4* xr = (const float4*)(x + ((long)b * 1024 + m) * 512);
  const float4* gr = (const float4*)(g2t + (long)(31 - m + j) * 512);
  float4 a0 = xr[lane * 2], a1 = xr[lane * 2 + 1];
  float4 c0 = gr[lane * 2], c1 = gr[lane * 2 + 1];
  float s = a0.x * c0.x + a0.y * c0.y + a0.z * c0.z + a0.w * c0.w
          + a1.x * c1.x + a1.y * c1.y + a1.z * c1.z + a1.w * c1.w;
#pragma unroll
  for (int off = 32; off; off >>= 1) s += __shfl_down(s, off);
  if (lane == 0) S[gid] = s;
}

// Stage B: per-b 32x32 scan + relu/tril + exact rowsum + overwrite wrelu.
__global__ __launch_bounds__(1024) void small_scan(
    const float* __restrict__ Sg, __bf16* __restrict__ wrelu, float* __restrict__ rowsum) {
  int b = blockIdx.x, tid = threadIdx.x;
  __shared__ float S[32][33];
  int m = tid >> 5, j = tid & 31;
  S[m][j] = Sg[b * 1024 + tid];
  __syncthreads();
  if (tid < 32) { // cumsum over m for column j=tid
    float run = 0.f;
    for (int mm = 0; mm < 32; ++mm) { run += S[mm][tid]; S[mm][tid] = run; }
  }
  __syncthreads();
  float v = (j <= m) ? fmaxf(S[m][j], 0.f) : 0.f;
  wrelu[((long)b * 1024 + m) * 1024 + j] = (__bf16)v;
  float rs = v;
#pragma unroll
  for (int off = 16; off; off >>= 1) rs += __shfl_down(rs, off, 32);
  if (j == 0) rowsum[b * 1024 + m] = rs;
}

// ---------------------------------------------------------------------------
extern "C" void kernel_launch(void* const* d_in, const int* in_sizes, int n_in,
                              void* d_out, int out_size, void* d_ws, size_t ws_size,
                              hipStream_t stream) {
  const float* x   = (const float*)d_in[0];
  const float* gen = (const float*)d_in[1];
  const float* Wq  = (const float*)d_in[2];
  const float* Wv  = (const float*)d_in[3];
  const float* Wc  = (const float*)d_in[4];

  char* ws = (char*)d_ws;
  __bf16* xb    = (__bf16*)(ws + 0L);
  __bf16* vT    = (__bf16*)(ws + 33554432L);
  __bf16* wfull = (__bf16*)(ws + 67108864L);
  __bf16* wrelu = (__bf16*)(ws + 134217728L);
  __bf16* genT  = (__bf16*)(ws + 167772160L);
  __bf16* wqT   = (__bf16*)(ws + 169869312L);   // Wq^T bf16 (old wqb slot)
  __bf16* wvT   = (__bf16*)(ws + 170393600L);   // Wv^T bf16 (old wvb slot)
  __bf16* wcb   = (__bf16*)(ws + 170917888L);
  float*  g2t   = (float*)(ws + 171442176L);
  // overlays in the dead qb region (16 MiB at 16777216):
  float*  csum  = (float*)(ws + 16777216L);            // 2 MiB (16*32*1024 f32)
  float*  rsum  = (float*)(ws + 16777216L + 2097152L); // 64 KiB
  float*  Sbuf  = (float*)(ws + 16777216L + 2162688L); // 64 KiB
  // overlays in the dead outn region (16 MiB at 50331648):
  __bf16* Pmat  = (__bf16*)(ws + 50331648L);           // 512x512 bf16 (Wc@Wv)
  __bf16* Bg    = (__bf16*)(ws + 51380224L);           // 2048x512 bf16 (gen^T@Wq^T)
  float*  gp    = (float*)(ws + 58720256L);            // 1 MiB g2t partials

  // conversions / transposes
  f2bf_kernel<<<8192, 256, 0, stream>>>(x, xb, 2097152);
  f2bf_kernel<<<256, 256, 0, stream>>>(Wc, wcb, 65536);
  transpose_f2bf<<<dim3(8, 8), 256, 0, stream>>>(Wq, wqT);
  transpose_f2bf<<<dim3(8, 8), 256, 0, stream>>>(Wv, wvT);
  genT_kernel<<<2048, 256, 0, stream>>>(gen, genT);
  g2t_part<<<dim3(63, 8), 256, 0, stream>>>(Wq, gen, gp);
  g2t_reduce<<<126, 256, 0, stream>>>(gp, g2t);

  // Weight folding: P = Wc@Wv (for v-path), Bg = gen^T@Wq^T (for w-path)
  gemm_bt<1><<<dim3(4, 4, 1), 256, 0, stream>>>(wcb, wvT, Pmat, nullptr, 512, 512, 0, 0, 0, 0);
  gemm_bt<1><<<dim3(4, 16, 1), 256, 0, stream>>>(genT, wqT, Bg, nullptr, 512, 512, 0, 0, 0, 0);

  // vcT = (x @ P^T)^T per batch ; w_full = x @ Bg^T (trapezoid band)
  gemm_bt<2><<<dim3(4, 128, 1), 256, 0, stream>>>(xb, Pmat, vT, nullptr, 512, 512, 0, 0, 0, 0);
  gemm_bt<1, true><<<dim3(9, 128, 1), 256, 0, stream>>>(xb, Bg, wfull, nullptr, 2048, 512, 0, 0, 0, 0);

  // gather + cumsum + relu/tril + rowsum
  chunk_sums<<<dim3(4, 32, 16), 256, 0, stream>>>(wfull, csum);
  scan_kernel<<<64, 256, 0, stream>>>(csum);
  cumsum_relu<<<dim3(4, 32, 16), 256, 0, stream>>>(wfull, csum, wrelu);
  rowsum_kernel<<<4096, 256, 0, stream>>>(wrelu, rsum);

  // exact f32 fix for rows l<32
  small_dots<<<4096, 256, 0, stream>>>(x, g2t, Sbuf);
  small_scan<<<16, 1024, 0, stream>>>(Sbuf, wrelu, rsum);

  // OUT = normalize(Wrelu) @ vc  (batched, triangular) -> f32 d_out directly
  gemm_bt<4, false, true><<<dim3(4, 8, 16), 256, 0, stream>>>(wrelu, vT, d_out, rsum, 512, 1024,
                                                 1024L * 1024, 512L * 1024, 512L * 1024, 1024);
}

// Round 6
// 186.724 us; speedup vs baseline: 2.5388x; 1.0026x over previous
//
#include <hip/hip_runtime.h>
#include <hip/hip_bf16.h>

typedef __attribute__((ext_vector_type(8))) __bf16 bf16x8;
typedef __attribute__((ext_vector_type(4))) __bf16 bf16x4;
typedef __attribute__((ext_vector_type(4))) float  f32x4;

// ---------------------------------------------------------------------------
// async global->LDS, 16B per lane. LDS dest must be wave-uniform base.
__device__ __forceinline__ void gl_lds16(const __bf16* g, __bf16* l) {
  __builtin_amdgcn_global_load_lds(
      (const __attribute__((address_space(1))) void*)g,
      (__attribute__((address_space(3))) void*)l,
      16, 0, 0);
}

// ---------------------------------------------------------------------------
// f32 -> bf16 conversion, float4 vectorized
__global__ void f2bf_kernel(const float* __restrict__ in, __bf16* __restrict__ out, int n4) {
  int i = blockIdx.x * blockDim.x + threadIdx.x;
  if (i >= n4) return;
  float4 v = ((const float4*)in)[i];
  bf16x4 o;
  o[0] = (__bf16)v.x; o[1] = (__bf16)v.y; o[2] = (__bf16)v.z; o[3] = (__bf16)v.w;
  *(bf16x4*)(out + 4L * i) = o;
}

// 512x512 f32 -> bf16 transposed (out[e][d] = in[d][e]), LDS-tiled.
__global__ void transpose_f2bf(const float* __restrict__ in, __bf16* __restrict__ out) {
  __shared__ float S[64][65];
  int tx = threadIdx.x & 63, ty = threadIdx.x >> 6; // 64 x 4
  int d0 = blockIdx.y * 64, e0 = blockIdx.x * 64;
#pragma unroll
  for (int i = 0; i < 16; ++i) {
    int di = i * 4 + ty;
    S[di][tx] = in[(long)(d0 + di) * 512 + e0 + tx];
  }
  __syncthreads();
#pragma unroll
  for (int i = 0; i < 16; ++i) {
    int ei = i * 4 + ty;
    out[(long)(e0 + ei) * 512 + d0 + tx] = (__bf16)S[tx][ei];
  }
}

// gen (512 x 2047) f32 -> genT (2048 x 512) bf16, row 2047 zero-padded
__global__ void genT_kernel(const float* __restrict__ gen, __bf16* __restrict__ genT) {
  int i = blockIdx.x; // 0..2047
  for (int d = threadIdx.x; d < 512; d += blockDim.x) {
    float v = (i < 2047) ? gen[(long)d * 2047 + i] : 0.f;
    genT[(long)i * 512 + d] = (__bf16)v;
  }
}

// ---------------------------------------------------------------------------
// g2t[i][k] = sum_d Wq[d][k] * gen[d][992+i],  i in [0,63)  (f32 exact path)
__global__ void g2t_part(const float* __restrict__ Wq, const float* __restrict__ gen,
                         float* __restrict__ gp) {
  int i = blockIdx.x;   // 0..62
  int c = blockIdx.y;   // 0..7
  int k = threadIdx.x;  // 0..255
  int d0 = c * 64;
  float a0 = 0.f, a1 = 0.f;
#pragma unroll 8
  for (int t = 0; t < 64; ++t) {
    int d = d0 + t;
    float g = gen[(long)d * 2047 + 992 + i];
    a0 += Wq[(long)d * 512 + k] * g;
    a1 += Wq[(long)d * 512 + k + 256] * g;
  }
  long o = ((long)c * 63 + i) * 512;
  gp[o + k] = a0;
  gp[o + k + 256] = a1;
}

__global__ void g2t_reduce(const float* __restrict__ gp, float* __restrict__ g2t) {
  int idx = blockIdx.x * 256 + threadIdx.x; // 0..32255
  if (idx >= 63 * 512) return;
  float s = 0.f;
#pragma unroll
  for (int c = 0; c < 8; ++c) s += gp[(long)c * 63 * 512 + idx];
  g2t[idx] = s;
}

// ---------------------------------------------------------------------------
// bf16 GEMM, C = A @ B^T (m97 structure: 128x128 tile, BK=32, 4 waves).
// MODE 1: store bf16 C (ldc=N).
// MODE 4: f32 C scaled per-row by 1/(aux[row]+1e-8) (direct d_out write).
// TRIL: A lower-triangular in K -> K-loop ends at m0+128.
template <int MODE, bool TRIL = false>
__global__ __launch_bounds__(256) void gemm_bt(
    const __bf16* __restrict__ A, const __bf16* __restrict__ B, void* __restrict__ Cv,
    const float* __restrict__ aux, int N, int K, long sA, long sB, long sC, int sAux) {
  __shared__ __bf16 As[128 * 32];
  __shared__ __bf16 Bs[128 * 32];
  const int tid = threadIdx.x;
  const int w = tid >> 6, l = tid & 63;
  const int m0 = blockIdx.y * 128;
  const int n0 = blockIdx.x * 128;
  const int bz = blockIdx.z;
  const __bf16* Ab = A + (long)bz * sA;
  const __bf16* Bb = B + (long)bz * sB;

  const int srow = w * 16 + (l >> 2);
  const int scol = (l & 3) * 8;
  const int wr = (w >> 1) * 64, wc = (w & 1) * 64;
  const int fr = l & 15, fk = (l >> 4) * 8;

  f32x4 acc[4][4] = {};

  const int KM = TRIL ? min(K, m0 + 128) : K;
  for (int k0 = 0; k0 < KM; k0 += 32) {
    __syncthreads();
    gl_lds16(Ab + (long)(m0 + srow) * K + (k0 + scol),      &As[(w * 16) * 32]);
    gl_lds16(Ab + (long)(m0 + 64 + srow) * K + (k0 + scol), &As[(64 + w * 16) * 32]);
    gl_lds16(Bb + (long)(n0 + srow) * K + (k0 + scol),      &Bs[(w * 16) * 32]);
    gl_lds16(Bb + (long)(n0 + 64 + srow) * K + (k0 + scol), &Bs[(64 + w * 16) * 32]);
    __syncthreads();

    bf16x8 af[4], bg[4];
#pragma unroll
    for (int i = 0; i < 4; ++i) af[i] = *(const bf16x8*)&As[(wr + i * 16 + fr) * 32 + fk];
#pragma unroll
    for (int j = 0; j < 4; ++j) bg[j] = *(const bf16x8*)&Bs[(wc + j * 16 + fr) * 32 + fk];
#pragma unroll
    for (int i = 0; i < 4; ++i)
#pragma unroll
      for (int j = 0; j < 4; ++j)
        acc[i][j] = __builtin_amdgcn_mfma_f32_16x16x32_bf16(af[i], bg[j], acc[i][j], 0, 0, 0);
  }

  const int rbase = m0 + wr + ((l >> 4) << 2);
  const int cbase = n0 + wc + fr;

  if constexpr (MODE == 1) {
    __bf16* C = (__bf16*)Cv + (long)bz * sC;
#pragma unroll
    for (int i = 0; i < 4; ++i)
#pragma unroll
      for (int r = 0; r < 4; ++r) {
        long row = rbase + i * 16 + r;
#pragma unroll
        for (int j = 0; j < 4; ++j) C[row * N + cbase + j * 16] = (__bf16)acc[i][j][r];
      }
  } else { // MODE 4
    float* C = (float*)Cv + (long)bz * sC;
    const float* ax = aux + (long)bz * sAux;
#pragma unroll
    for (int i = 0; i < 4; ++i)
#pragma unroll
      for (int r = 0; r < 4; ++r) {
        long row = rbase + i * 16 + r;
        float sc = 1.f / (ax[row] + 1e-8f);
#pragma unroll
        for (int j = 0; j < 4; ++j) C[row * N + cbase + j * 16] = acc[i][j][r] * sc;
      }
  }
}

// ---------------------------------------------------------------------------
// Merged x-GEMM: A = xb (16384 x 512). Per m-tile y: 13 n-tiles.
//   xt in [0,9):  band tile vs Bg  -> store gathered S[row][jj], jj = col-1023+(row&1023)
//   xt in [9,13): vT tile vs Pmat -> store vT[(row>>10)*512 + col][row&1023]
// XCD-swizzled linear grid: 1664 = 8 * 208 blocks.
__global__ __launch_bounds__(256) void gemm_x(
    const __bf16* __restrict__ A, const __bf16* __restrict__ Bg,
    const __bf16* __restrict__ Pm, __bf16* __restrict__ S, __bf16* __restrict__ vT) {
  __shared__ __bf16 As[128 * 32];
  __shared__ __bf16 Bs[128 * 32];
  const int tid = threadIdx.x;
  const int w = tid >> 6, l = tid & 63;

  // bijective XCD swizzle (nwg=1664, 208 per XCD)
  int wgid = blockIdx.x;
  int swz = (wgid & 7) * 208 + (wgid >> 3);
  int y = swz / 13, xt = swz - y * 13;
  const bool band = (xt < 9);
  const int m0 = y * 128;
  const int n0 = band ? (7 - (y & 7) + xt) * 128 : (xt - 9) * 128;
  const __bf16* Bb = band ? Bg : Pm;
  const int K = 512;

  const int srow = w * 16 + (l >> 2);
  const int scol = (l & 3) * 8;
  const int wr = (w >> 1) * 64, wc = (w & 1) * 64;
  const int fr = l & 15, fk = (l >> 4) * 8;

  f32x4 acc[4][4] = {};

  for (int k0 = 0; k0 < K; k0 += 32) {
    __syncthreads();
    gl_lds16(A + (long)(m0 + srow) * K + (k0 + scol),       &As[(w * 16) * 32]);
    gl_lds16(A + (long)(m0 + 64 + srow) * K + (k0 + scol),  &As[(64 + w * 16) * 32]);
    gl_lds16(Bb + (long)(n0 + srow) * K + (k0 + scol),      &Bs[(w * 16) * 32]);
    gl_lds16(Bb + (long)(n0 + 64 + srow) * K + (k0 + scol), &Bs[(64 + w * 16) * 32]);
    __syncthreads();

    bf16x8 af[4], bg[4];
#pragma unroll
    for (int i = 0; i < 4; ++i) af[i] = *(const bf16x8*)&As[(wr + i * 16 + fr) * 32 + fk];
#pragma unroll
    for (int j = 0; j < 4; ++j) bg[j] = *(const bf16x8*)&Bs[(wc + j * 16 + fr) * 32 + fk];
#pragma unroll
    for (int i = 0; i < 4; ++i)
#pragma unroll
      for (int j = 0; j < 4; ++j)
        acc[i][j] = __builtin_amdgcn_mfma_f32_16x16x32_bf16(af[i], bg[j], acc[i][j], 0, 0, 0);
  }

  const int rbase = m0 + wr + ((l >> 4) << 2);
  const int cbase = n0 + wc + fr;

  if (band) {
#pragma unroll
    for (int i = 0; i < 4; ++i)
#pragma unroll
      for (int r = 0; r < 4; ++r) {
        int row = rbase + i * 16 + r;
        int lloc = row & 1023;
#pragma unroll
        for (int j = 0; j < 4; ++j) {
          int jj = cbase + j * 16 - 1023 + lloc;
          if ((unsigned)jj < 1024u)
            S[(long)row * 1024 + jj] = (__bf16)acc[i][j][r];
        }
      }
  } else {
#pragma unroll
    for (int i = 0; i < 4; ++i) {
      int gm = rbase + i * 16;
      int bt = gm >> 10, lloc = gm & 1023;
#pragma unroll
      for (int j = 0; j < 4; ++j) {
        bf16x4 pk;
        pk[0] = (__bf16)acc[i][j][0]; pk[1] = (__bf16)acc[i][j][1];
        pk[2] = (__bf16)acc[i][j][2]; pk[3] = (__bf16)acc[i][j][3];
        *(bf16x4*)&vT[((long)bt * 512 + cbase + j * 16) * 1024 + lloc] = pk;
      }
    }
  }
}

// ---------------------------------------------------------------------------
// Cumsum over l of S[b,l,j] (gathered scores), 32 chunks of 32.
__global__ void chunk_sums(const __bf16* __restrict__ S, float* __restrict__ csum) {
  int j = blockIdx.x * 256 + threadIdx.x;
  int c = blockIdx.y, b = blockIdx.z;
  const __bf16* Sb = S + (long)b * 1024 * 1024;
  float acc = 0.f;
  int l0 = c * 32;
  for (int l = l0; l < l0 + 32; ++l)
    acc += (float)Sb[(long)l * 1024 + j];
  csum[((long)(b * 32 + c) << 10) + j] = acc;
}

__global__ void scan_kernel(float* __restrict__ csum) {
  int idx = blockIdx.x * 256 + threadIdx.x; // 0..16383
  int b = idx >> 10, j = idx & 1023;
  long base = ((long)b * 32 << 10) + j;
  float v[32];
#pragma unroll
  for (int c = 0; c < 32; ++c) v[c] = csum[base + ((long)c << 10)];
  float s = 0.f;
#pragma unroll
  for (int c = 0; c < 32; ++c) { float t = v[c]; csum[base + ((long)c << 10)] = s; s += t; }
}

// walk chunk with offset, relu+tril, store bf16 weights, fused rowsum atomics
__global__ void cumsum_relu(const __bf16* __restrict__ S, const float* __restrict__ csum,
                            __bf16* __restrict__ wrelu, float* __restrict__ rowsum) {
  int j = blockIdx.x * 256 + threadIdx.x;
  int c = blockIdx.y, b = blockIdx.z;
  float run = csum[((long)(b * 32 + c) << 10) + j];
  const __bf16* Sb = S + (long)b * 1024 * 1024;
  __bf16* wr = wrelu + (long)b * 1024 * 1024;
  int l0 = c * 32;
  for (int l = l0; l < l0 + 32; ++l) {
    run += (float)Sb[(long)l * 1024 + j];
    float v = (j <= l) ? fmaxf(run, 0.f) : 0.f;
    wr[(long)l * 1024 + j] = (__bf16)v;
    float s = v;
#pragma unroll
    for (int off = 32; off; off >>= 1) s += __shfl_down(s, off);
    if ((threadIdx.x & 63) == 0 && s != 0.f) atomicAdd(&rowsum[b * 1024 + l], s);
  }
}

// ---------------------------------------------------------------------------
// Exact f32 path for rows l<32 (sign-flip hazard region).
__global__ __launch_bounds__(256) void small_dots(
    const float* __restrict__ x, const float* __restrict__ g2t, float* __restrict__ S) {
  int gid = blockIdx.x * 4 + (threadIdx.x >> 6); // 0..16383
  int lane = threadIdx.x & 63;
  int b = gid >> 10, rem = gid & 1023, m = rem >> 5, j = rem & 31;
  const float4* xr = (const float4*)(x + ((long)b * 1024 + m) * 512);
  const float4* gr = (const float4*)(g2t + (long)(31 - m + j) * 512);
  float4 a0 = xr[lane * 2], a1 = xr[lane * 2 + 1];
  float4 c0 = gr[lane * 2], c1 = gr[lane * 2 + 1];
  float s = a0.x * c0.x + a0.y * c0.y + a0.z * c0.z + a0.w * c0.w
          + a1.x * c1.x + a1.y * c1.y + a1.z * c1.z + a1.w * c1.w;
#pragma unroll
  for (int off = 32; off; off >>= 1) s += __shfl_down(s, off);
  if (lane == 0) S[gid] = s;
}

__global__ __launch_bounds__(1024) void small_scan(
    const float* __restrict__ Sg, __bf16* __restrict__ wrelu, float* __restrict__ rowsum) {
  int b = blockIdx.x, tid = threadIdx.x;
  __shared__ float S[32][33];
  int m = tid >> 5, j = tid & 31;
  S[m][j] = Sg[b * 1024 + tid];
  __syncthreads();
  if (tid < 32) {
    float run = 0.f;
    for (int mm = 0; mm < 32; ++mm) { run += S[mm][tid]; S[mm][tid] = run; }
  }
  __syncthreads();
  float v = (j <= m) ? fmaxf(S[m][j], 0.f) : 0.f;
  wrelu[((long)b * 1024 + m) * 1024 + j] = (__bf16)v;
  float rs = v;
#pragma unroll
  for (int off = 16; off; off >>= 1) rs += __shfl_down(rs, off, 32);
  if (j == 0) rowsum[b * 1024 + m] = rs;
}

// ---------------------------------------------------------------------------
extern "C" void kernel_launch(void* const* d_in, const int* in_sizes, int n_in,
                              void* d_out, int out_size, void* d_ws, size_t ws_size,
                              hipStream_t stream) {
  const float* x   = (const float*)d_in[0];
  const float* gen = (const float*)d_in[1];
  const float* Wq  = (const float*)d_in[2];
  const float* Wv  = (const float*)d_in[3];
  const float* Wc  = (const float*)d_in[4];

  char* ws = (char*)d_ws;
  __bf16* xb    = (__bf16*)(ws + 0L);
  __bf16* vT    = (__bf16*)(ws + 33554432L);
  __bf16* Smat  = (__bf16*)(ws + 67108864L);   // gathered scores, 32 MiB
  __bf16* wrelu = (__bf16*)(ws + 134217728L);
  __bf16* genT  = (__bf16*)(ws + 167772160L);
  __bf16* wqT   = (__bf16*)(ws + 169869312L);
  __bf16* wvT   = (__bf16*)(ws + 170393600L);
  __bf16* wcb   = (__bf16*)(ws + 170917888L);
  float*  g2t   = (float*)(ws + 171442176L);
  // overlays in the free region at 16 MiB:
  float*  csum  = (float*)(ws + 16777216L);            // 2 MiB
  float*  rsum  = (float*)(ws + 16777216L + 2097152L); // 64 KiB
  float*  Sbuf  = (float*)(ws + 16777216L + 2162688L); // 64 KiB
  // overlays in the free region at 48 MiB:
  __bf16* Pmat  = (__bf16*)(ws + 50331648L);           // 512x512 bf16 (Wc@Wv)
  __bf16* Bg    = (__bf16*)(ws + 51380224L);           // 2048x512 bf16 (gen^T@Wq^T)
  float*  gp    = (float*)(ws + 58720256L);            // 1 MiB g2t partials

  // conversions / transposes
  f2bf_kernel<<<8192, 256, 0, stream>>>(x, xb, 2097152);
  f2bf_kernel<<<256, 256, 0, stream>>>(Wc, wcb, 65536);
  transpose_f2bf<<<dim3(8, 8), 256, 0, stream>>>(Wq, wqT);
  transpose_f2bf<<<dim3(8, 8), 256, 0, stream>>>(Wv, wvT);
  genT_kernel<<<2048, 256, 0, stream>>>(gen, genT);
  g2t_part<<<dim3(63, 8), 256, 0, stream>>>(Wq, gen, gp);
  g2t_reduce<<<126, 256, 0, stream>>>(gp, g2t);

  // Weight folding: P = Wc@Wv, Bg = gen^T@Wq^T
  gemm_bt<1><<<dim3(4, 4, 1), 256, 0, stream>>>(wcb, wvT, Pmat, nullptr, 512, 512, 0, 0, 0, 0);
  gemm_bt<1><<<dim3(4, 16, 1), 256, 0, stream>>>(genT, wqT, Bg, nullptr, 512, 512, 0, 0, 0, 0);

  // merged: gathered S = band(x@Bg^T) ; vT = (x@P^T)^T   (XCD-swizzled)
  gemm_x<<<1664, 256, 0, stream>>>(xb, Bg, Pmat, Smat, vT);

  // cumsum + relu/tril + fused rowsum
  chunk_sums<<<dim3(4, 32, 16), 256, 0, stream>>>(Smat, csum);
  scan_kernel<<<64, 256, 0, stream>>>(csum);
  hipMemsetAsync(rsum, 0, 16 * 1024 * 4, stream);
  cumsum_relu<<<dim3(4, 32, 16), 256, 0, stream>>>(Smat, csum, wrelu, rsum);

  // exact f32 fix for rows l<32
  small_dots<<<4096, 256, 0, stream>>>(x, g2t, Sbuf);
  small_scan<<<16, 1024, 0, stream>>>(Sbuf, wrelu, rsum);

  // OUT = normalize(Wrelu) @ vc  (batched, triangular) -> f32 d_out directly
  gemm_bt<4, true><<<dim3(4, 8, 16), 256, 0, stream>>>(wrelu, vT, d_out, rsum, 512, 1024,
                                                 1024L * 1024, 512L * 1024, 512L * 1024, 1024);
}

// Round 7
// 181.323 us; speedup vs baseline: 2.6144x; 1.0298x over previous
//
#include <hip/hip_runtime.h>
#include <hip/hip_bf16.h>

typedef __attribute__((ext_vector_type(8))) __bf16 bf16x8;
typedef __attribute__((ext_vector_type(4))) __bf16 bf16x4;
typedef __attribute__((ext_vector_type(4))) float  f32x4;

// ---------------------------------------------------------------------------
// async global->LDS, 16B per lane. LDS dest must be wave-uniform base.
__device__ __forceinline__ void gl_lds16(const __bf16* g, __bf16* l) {
  __builtin_amdgcn_global_load_lds(
      (const __attribute__((address_space(1))) void*)g,
      (__attribute__((address_space(3))) void*)l,
      16, 0, 0);
}

// ---------------------------------------------------------------------------
// f32 -> bf16 conversion, float4 vectorized
__global__ void f2bf_kernel(const float* __restrict__ in, __bf16* __restrict__ out, int n4) {
  int i = blockIdx.x * blockDim.x + threadIdx.x;
  if (i >= n4) return;
  float4 v = ((const float4*)in)[i];
  bf16x4 o;
  o[0] = (__bf16)v.x; o[1] = (__bf16)v.y; o[2] = (__bf16)v.z; o[3] = (__bf16)v.w;
  *(bf16x4*)(out + 4L * i) = o;
}

// 512x512 f32 -> bf16 transposed (out[e][d] = in[d][e]), LDS-tiled.
__global__ void transpose_f2bf(const float* __restrict__ in, __bf16* __restrict__ out) {
  __shared__ float S[64][65];
  int tx = threadIdx.x & 63, ty = threadIdx.x >> 6; // 64 x 4
  int d0 = blockIdx.y * 64, e0 = blockIdx.x * 64;
#pragma unroll
  for (int i = 0; i < 16; ++i) {
    int di = i * 4 + ty;
    S[di][tx] = in[(long)(d0 + di) * 512 + e0 + tx];
  }
  __syncthreads();
#pragma unroll
  for (int i = 0; i < 16; ++i) {
    int ei = i * 4 + ty;
    out[(long)(e0 + ei) * 512 + d0 + tx] = (__bf16)S[tx][ei];
  }
}

// gen (512 x 2047) f32 -> genT (2048 x 512) bf16, row 2047 zero-padded
__global__ void genT_kernel(const float* __restrict__ gen, __bf16* __restrict__ genT) {
  int i = blockIdx.x; // 0..2047
  for (int d = threadIdx.x; d < 512; d += blockDim.x) {
    float v = (i < 2047) ? gen[(long)d * 2047 + i] : 0.f;
    genT[(long)i * 512 + d] = (__bf16)v;
  }
}

// ---------------------------------------------------------------------------
// g2t[i][k] = sum_d Wq[d][k] * gen[d][992+i],  i in [0,63)  (f32 exact path)
__global__ void g2t_part(const float* __restrict__ Wq, const float* __restrict__ gen,
                         float* __restrict__ gp) {
  int i = blockIdx.x;   // 0..62
  int c = blockIdx.y;   // 0..7
  int k = threadIdx.x;  // 0..255
  int d0 = c * 64;
  float a0 = 0.f, a1 = 0.f;
#pragma unroll 8
  for (int t = 0; t < 64; ++t) {
    int d = d0 + t;
    float g = gen[(long)d * 2047 + 992 + i];
    a0 += Wq[(long)d * 512 + k] * g;
    a1 += Wq[(long)d * 512 + k + 256] * g;
  }
  long o = ((long)c * 63 + i) * 512;
  gp[o + k] = a0;
  gp[o + k + 256] = a1;
}

__global__ void g2t_reduce(const float* __restrict__ gp, float* __restrict__ g2t) {
  int idx = blockIdx.x * 256 + threadIdx.x; // 0..32255
  if (idx >= 63 * 512) return;
  float s = 0.f;
#pragma unroll
  for (int c = 0; c < 8; ++c) s += gp[(long)c * 63 * 512 + idx];
  g2t[idx] = s;
}

// ---------------------------------------------------------------------------
// bf16 GEMM, C = A @ B^T. 128x128 tile, BK=32, 4 waves, 2-phase double-buffered
// LDS (stage t+1 issued before compute of t; one barrier per K-step).
// MODE 1: store bf16 C (ldc=N).
// MODE 4: f32 C scaled per-row by 1/(aux[row]+1e-8) (direct d_out write).
// TRIL: A lower-triangular in K -> K-loop ends at m0+128.
template <int MODE, bool TRIL = false>
__global__ __launch_bounds__(256) void gemm_bt(
    const __bf16* __restrict__ A, const __bf16* __restrict__ B, void* __restrict__ Cv,
    const float* __restrict__ aux, int N, int K, long sA, long sB, long sC, int sAux) {
  __shared__ __bf16 As[2][128 * 32];
  __shared__ __bf16 Bs[2][128 * 32];
  const int tid = threadIdx.x;
  const int w = tid >> 6, l = tid & 63;
  const int m0 = blockIdx.y * 128;
  const int n0 = blockIdx.x * 128;
  const int bz = blockIdx.z;
  const __bf16* Ab = A + (long)bz * sA;
  const __bf16* Bb = B + (long)bz * sB;

  const int srow = w * 16 + (l >> 2);
  const int scol = (l & 3) * 8;
  const int wr = (w >> 1) * 64, wc = (w & 1) * 64;
  const int fr = l & 15, fk = (l >> 4) * 8;

  f32x4 acc[4][4] = {};

  const int KM = TRIL ? min(K, m0 + 128) : K;
  const int nt = KM >> 5;

  // prologue: stage tile 0 into buffer 0
  gl_lds16(Ab + (long)(m0 + srow) * K + scol,      &As[0][(w * 16) * 32]);
  gl_lds16(Ab + (long)(m0 + 64 + srow) * K + scol, &As[0][(64 + w * 16) * 32]);
  gl_lds16(Bb + (long)(n0 + srow) * K + scol,      &Bs[0][(w * 16) * 32]);
  gl_lds16(Bb + (long)(n0 + 64 + srow) * K + scol, &Bs[0][(64 + w * 16) * 32]);
  __syncthreads();

  int cur = 0;
  for (int t = 0; t < nt; ++t) {
    if (t + 1 < nt) {
      const int k0 = (t + 1) << 5;
      const int nx = cur ^ 1;
      gl_lds16(Ab + (long)(m0 + srow) * K + (k0 + scol),      &As[nx][(w * 16) * 32]);
      gl_lds16(Ab + (long)(m0 + 64 + srow) * K + (k0 + scol), &As[nx][(64 + w * 16) * 32]);
      gl_lds16(Bb + (long)(n0 + srow) * K + (k0 + scol),      &Bs[nx][(w * 16) * 32]);
      gl_lds16(Bb + (long)(n0 + 64 + srow) * K + (k0 + scol), &Bs[nx][(64 + w * 16) * 32]);
    }
    bf16x8 af[4], bg[4];
#pragma unroll
    for (int i = 0; i < 4; ++i) af[i] = *(const bf16x8*)&As[cur][(wr + i * 16 + fr) * 32 + fk];
#pragma unroll
    for (int j = 0; j < 4; ++j) bg[j] = *(const bf16x8*)&Bs[cur][(wc + j * 16 + fr) * 32 + fk];
#pragma unroll
    for (int i = 0; i < 4; ++i)
#pragma unroll
      for (int j = 0; j < 4; ++j)
        acc[i][j] = __builtin_amdgcn_mfma_f32_16x16x32_bf16(af[i], bg[j], acc[i][j], 0, 0, 0);
    __syncthreads();   // drains vmcnt (stage t+1 residual) + lgkm; protects buffer reuse
    cur ^= 1;
  }

  const int rbase = m0 + wr + ((l >> 4) << 2);
  const int cbase = n0 + wc + fr;

  if constexpr (MODE == 1) {
    __bf16* C = (__bf16*)Cv + (long)bz * sC;
#pragma unroll
    for (int i = 0; i < 4; ++i)
#pragma unroll
      for (int r = 0; r < 4; ++r) {
        long row = rbase + i * 16 + r;
#pragma unroll
        for (int j = 0; j < 4; ++j) C[row * N + cbase + j * 16] = (__bf16)acc[i][j][r];
      }
  } else { // MODE 4
    float* C = (float*)Cv + (long)bz * sC;
    const float* ax = aux + (long)bz * sAux;
#pragma unroll
    for (int i = 0; i < 4; ++i)
#pragma unroll
      for (int r = 0; r < 4; ++r) {
        long row = rbase + i * 16 + r;
        float sc = 1.f / (ax[row] + 1e-8f);
#pragma unroll
        for (int j = 0; j < 4; ++j) C[row * N + cbase + j * 16] = acc[i][j][r] * sc;
      }
  }
}

// ---------------------------------------------------------------------------
// Merged x-GEMM (2-phase double-buffered): A = xb (16384 x 512), 13 n-tiles/m-tile.
//   xt in [0,9):  band tile vs Bg  -> store gathered S[row][jj], jj = col-1023+(row&1023)
//   xt in [9,13): vT tile vs Pmat -> store vT[(row>>10)*512 + col][row&1023]
// XCD-swizzled linear grid: 1664 = 8 * 208 blocks.
__global__ __launch_bounds__(256) void gemm_x(
    const __bf16* __restrict__ A, const __bf16* __restrict__ Bg,
    const __bf16* __restrict__ Pm, __bf16* __restrict__ S, __bf16* __restrict__ vT) {
  __shared__ __bf16 As[2][128 * 32];
  __shared__ __bf16 Bs[2][128 * 32];
  const int tid = threadIdx.x;
  const int w = tid >> 6, l = tid & 63;

  // bijective XCD swizzle (nwg=1664, 208 per XCD)
  int wgid = blockIdx.x;
  int swz = (wgid & 7) * 208 + (wgid >> 3);
  int y = swz / 13, xt = swz - y * 13;
  const bool band = (xt < 9);
  const int m0 = y * 128;
  const int n0 = band ? (7 - (y & 7) + xt) * 128 : (xt - 9) * 128;
  const __bf16* Bb = band ? Bg : Pm;
  const int K = 512;

  const int srow = w * 16 + (l >> 2);
  const int scol = (l & 3) * 8;
  const int wr = (w >> 1) * 64, wc = (w & 1) * 64;
  const int fr = l & 15, fk = (l >> 4) * 8;

  f32x4 acc[4][4] = {};

  // prologue
  gl_lds16(A + (long)(m0 + srow) * K + scol,       &As[0][(w * 16) * 32]);
  gl_lds16(A + (long)(m0 + 64 + srow) * K + scol,  &As[0][(64 + w * 16) * 32]);
  gl_lds16(Bb + (long)(n0 + srow) * K + scol,      &Bs[0][(w * 16) * 32]);
  gl_lds16(Bb + (long)(n0 + 64 + srow) * K + scol, &Bs[0][(64 + w * 16) * 32]);
  __syncthreads();

  int cur = 0;
  for (int t = 0; t < 16; ++t) {
    if (t + 1 < 16) {
      const int k0 = (t + 1) << 5;
      const int nx = cur ^ 1;
      gl_lds16(A + (long)(m0 + srow) * K + (k0 + scol),       &As[nx][(w * 16) * 32]);
      gl_lds16(A + (long)(m0 + 64 + srow) * K + (k0 + scol),  &As[nx][(64 + w * 16) * 32]);
      gl_lds16(Bb + (long)(n0 + srow) * K + (k0 + scol),      &Bs[nx][(w * 16) * 32]);
      gl_lds16(Bb + (long)(n0 + 64 + srow) * K + (k0 + scol), &Bs[nx][(64 + w * 16) * 32]);
    }
    bf16x8 af[4], bg[4];
#pragma unroll
    for (int i = 0; i < 4; ++i) af[i] = *(const bf16x8*)&As[cur][(wr + i * 16 + fr) * 32 + fk];
#pragma unroll
    for (int j = 0; j < 4; ++j) bg[j] = *(const bf16x8*)&Bs[cur][(wc + j * 16 + fr) * 32 + fk];
#pragma unroll
    for (int i = 0; i < 4; ++i)
#pragma unroll
      for (int j = 0; j < 4; ++j)
        acc[i][j] = __builtin_amdgcn_mfma_f32_16x16x32_bf16(af[i], bg[j], acc[i][j], 0, 0, 0);
    __syncthreads();
    cur ^= 1;
  }

  const int rbase = m0 + wr + ((l >> 4) << 2);
  const int cbase = n0 + wc + fr;

  if (band) {
#pragma unroll
    for (int i = 0; i < 4; ++i)
#pragma unroll
      for (int r = 0; r < 4; ++r) {
        int row = rbase + i * 16 + r;
        int lloc = row & 1023;
#pragma unroll
        for (int j = 0; j < 4; ++j) {
          int jj = cbase + j * 16 - 1023 + lloc;
          if ((unsigned)jj < 1024u)
            S[(long)row * 1024 + jj] = (__bf16)acc[i][j][r];
        }
      }
  } else {
#pragma unroll
    for (int i = 0; i < 4; ++i) {
      int gm = rbase + i * 16;
      int bt = gm >> 10, lloc = gm & 1023;
#pragma unroll
      for (int j = 0; j < 4; ++j) {
        bf16x4 pk;
        pk[0] = (__bf16)acc[i][j][0]; pk[1] = (__bf16)acc[i][j][1];
        pk[2] = (__bf16)acc[i][j][2]; pk[3] = (__bf16)acc[i][j][3];
        *(bf16x4*)&vT[((long)bt * 512 + cbase + j * 16) * 1024 + lloc] = pk;
      }
    }
  }
}

// ---------------------------------------------------------------------------
// Cumsum over l of S[b,l,j], 32 chunks of 32, bf16x8-vectorized (8 j per thread).
__global__ __launch_bounds__(128) void chunk_sums(const __bf16* __restrict__ S,
                                                  float* __restrict__ csum) {
  int j0 = threadIdx.x * 8;
  int c = blockIdx.x, b = blockIdx.y;
  const __bf16* Sb = S + (long)b * 1024 * 1024;
  float a[8] = {};
  int l0 = c * 32;
  for (int l = l0; l < l0 + 32; ++l) {
    bf16x8 v = *(const bf16x8*)&Sb[(long)l * 1024 + j0];
#pragma unroll
    for (int k = 0; k < 8; ++k) a[k] += (float)v[k];
  }
  long o = ((long)(b * 32 + c) << 10) + j0;
#pragma unroll
  for (int k = 0; k < 8; ++k) csum[o + k] = a[k];
}

__global__ void scan_kernel(float* __restrict__ csum) {
  int idx = blockIdx.x * 256 + threadIdx.x; // 0..16383
  int b = idx >> 10, j = idx & 1023;
  long base = ((long)b * 32 << 10) + j;
  float v[32];
#pragma unroll
  for (int c = 0; c < 32; ++c) v[c] = csum[base + ((long)c << 10)];
  float s = 0.f;
#pragma unroll
  for (int c = 0; c < 32; ++c) { float t = v[c]; csum[base + ((long)c << 10)] = s; s += t; }
}

// walk chunk with offset, relu+tril, bf16x8 store, fused rowsum atomics
__global__ __launch_bounds__(128) void cumsum_relu(const __bf16* __restrict__ S,
                                                   const float* __restrict__ csum,
                                                   __bf16* __restrict__ wrelu,
                                                   float* __restrict__ rowsum) {
  int j0 = threadIdx.x * 8;
  int c = blockIdx.x, b = blockIdx.y;
  float run[8];
  long co = ((long)(b * 32 + c) << 10) + j0;
#pragma unroll
  for (int k = 0; k < 8; ++k) run[k] = csum[co + k];
  const __bf16* Sb = S + (long)b * 1024 * 1024;
  __bf16* wr = wrelu + (long)b * 1024 * 1024;
  int l0 = c * 32;
  for (int l = l0; l < l0 + 32; ++l) {
    bf16x8 v = *(const bf16x8*)&Sb[(long)l * 1024 + j0];
    bf16x8 o;
    float rs = 0.f;
#pragma unroll
    for (int k = 0; k < 8; ++k) {
      run[k] += (float)v[k];
      float val = (j0 + k <= l) ? fmaxf(run[k], 0.f) : 0.f;
      o[k] = (__bf16)val;
      rs += val;
    }
    *(bf16x8*)&wr[(long)l * 1024 + j0] = o;
#pragma unroll
    for (int off = 32; off; off >>= 1) rs += __shfl_down(rs, off);
    if ((threadIdx.x & 63) == 0 && rs != 0.f) atomicAdd(&rowsum[b * 1024 + l], rs);
  }
}

// ---------------------------------------------------------------------------
// Exact f32 path for rows l<32 (sign-flip hazard region).
__global__ __launch_bounds__(256) void small_dots(
    const float* __restrict__ x, const float* __restrict__ g2t, float* __restrict__ S) {
  int gid = blockIdx.x * 4 + (threadIdx.x >> 6); // 0..16383
  int lane = threadIdx.x & 63;
  int b = gid >> 10, rem = gid & 1023, m = rem >> 5, j = rem & 31;
  const float4* xr = (const float4*)(x + ((long)b * 1024 + m) * 512);
  const float4* gr = (const float4*)(g2t + (long)(31 - m + j) * 512);
  float4 a0 = xr[lane * 2], a1 = xr[lane * 2 + 1];
  float4 c0 = gr[lane * 2], c1 = gr[lane * 2 + 1];
  float s = a0.x * c0.x + a0.y * c0.y + a0.z * c0.z + a0.w * c0.w
          + a1.x * c1.x + a1.y * c1.y + a1.z * c1.z + a1.w * c1.w;
#pragma unroll
  for (int off = 32; off; off >>= 1) s += __shfl_down(s, off);
  if (lane == 0) S[gid] = s;
}

__global__ __launch_bounds__(1024) void small_scan(
    const float* __restrict__ Sg, __bf16* __restrict__ wrelu, float* __restrict__ rowsum) {
  int b = blockIdx.x, tid = threadIdx.x;
  __shared__ float S[32][33];
  int m = tid >> 5, j = tid & 31;
  S[m][j] = Sg[b * 1024 + tid];
  __syncthreads();
  if (tid < 32) {
    float run = 0.f;
    for (int mm = 0; mm < 32; ++mm) { run += S[mm][tid]; S[mm][tid] = run; }
  }
  __syncthreads();
  float v = (j <= m) ? fmaxf(S[m][j], 0.f) : 0.f;
  wrelu[((long)b * 1024 + m) * 1024 + j] = (__bf16)v;
  float rs = v;
#pragma unroll
  for (int off = 16; off; off >>= 1) rs += __shfl_down(rs, off, 32);
  if (j == 0) rowsum[b * 1024 + m] = rs;
}

// ---------------------------------------------------------------------------
extern "C" void kernel_launch(void* const* d_in, const int* in_sizes, int n_in,
                              void* d_out, int out_size, void* d_ws, size_t ws_size,
                              hipStream_t stream) {
  const float* x   = (const float*)d_in[0];
  const float* gen = (const float*)d_in[1];
  const float* Wq  = (const float*)d_in[2];
  const float* Wv  = (const float*)d_in[3];
  const float* Wc  = (const float*)d_in[4];

  char* ws = (char*)d_ws;
  __bf16* xb    = (__bf16*)(ws + 0L);
  __bf16* vT    = (__bf16*)(ws + 33554432L);
  __bf16* Smat  = (__bf16*)(ws + 67108864L);   // gathered scores, 32 MiB
  __bf16* wrelu = (__bf16*)(ws + 134217728L);
  __bf16* genT  = (__bf16*)(ws + 167772160L);
  __bf16* wqT   = (__bf16*)(ws + 169869312L);
  __bf16* wvT   = (__bf16*)(ws + 170393600L);
  __bf16* wcb   = (__bf16*)(ws + 170917888L);
  float*  g2t   = (float*)(ws + 171442176L);
  // overlays in the free region at 16 MiB:
  float*  csum  = (float*)(ws + 16777216L);            // 2 MiB
  float*  rsum  = (float*)(ws + 16777216L + 2097152L); // 64 KiB
  float*  Sbuf  = (float*)(ws + 16777216L + 2162688L); // 64 KiB
  // overlays in the free region at 48 MiB:
  __bf16* Pmat  = (__bf16*)(ws + 50331648L);           // 512x512 bf16 (Wc@Wv)
  __bf16* Bg    = (__bf16*)(ws + 51380224L);           // 2048x512 bf16 (gen^T@Wq^T)
  float*  gp    = (float*)(ws + 58720256L);            // 1 MiB g2t partials

  // conversions / transposes
  f2bf_kernel<<<8192, 256, 0, stream>>>(x, xb, 2097152);
  f2bf_kernel<<<256, 256, 0, stream>>>(Wc, wcb, 65536);
  transpose_f2bf<<<dim3(8, 8), 256, 0, stream>>>(Wq, wqT);
  transpose_f2bf<<<dim3(8, 8), 256, 0, stream>>>(Wv, wvT);
  genT_kernel<<<2048, 256, 0, stream>>>(gen, genT);
  g2t_part<<<dim3(63, 8), 256, 0, stream>>>(Wq, gen, gp);
  g2t_reduce<<<126, 256, 0, stream>>>(gp, g2t);

  // Weight folding: P = Wc@Wv, Bg = gen^T@Wq^T
  gemm_bt<1><<<dim3(4, 4, 1), 256, 0, stream>>>(wcb, wvT, Pmat, nullptr, 512, 512, 0, 0, 0, 0);
  gemm_bt<1><<<dim3(4, 16, 1), 256, 0, stream>>>(genT, wqT, Bg, nullptr, 512, 512, 0, 0, 0, 0);

  // merged: gathered S = band(x@Bg^T) ; vT = (x@P^T)^T   (XCD-swizzled)
  gemm_x<<<1664, 256, 0, stream>>>(xb, Bg, Pmat, Smat, vT);

  // cumsum + relu/tril + fused rowsum
  chunk_sums<<<dim3(32, 16), 128, 0, stream>>>(Smat, csum);
  scan_kernel<<<64, 256, 0, stream>>>(csum);
  hipMemsetAsync(rsum, 0, 16 * 1024 * 4, stream);
  cumsum_relu<<<dim3(32, 16), 128, 0, stream>>>(Smat, csum, wrelu, rsum);

  // exact f32 fix for rows l<32
  small_dots<<<4096, 256, 0, stream>>>(x, g2t, Sbuf);
  small_scan<<<16, 1024, 0, stream>>>(Sbuf, wrelu, rsum);

  // OUT = normalize(Wrelu) @ vc  (batched, triangular) -> f32 d_out directly
  gemm_bt<4, true><<<dim3(4, 8, 16), 256, 0, stream>>>(wrelu, vT, d_out, rsum, 512, 1024,
                                                 1024L * 1024, 512L * 1024, 512L * 1024, 1024);
}